// Round 1
// baseline (1401.163 us; speedup 1.0000x reference)
//
#include <hip/hip_runtime.h>
#include <hip/hip_bf16.h>
#include <cstddef>

// ---------------------------------------------------------------------------
// Problem constants
// ---------------------------------------------------------------------------
static constexpr int T_ = 128, B_ = 16;
static constexpr int TB = T_ * B_;           // 2048
static constexpr int HID = 256, FEAT = 512, NACT = 18;

// Workspace layout (float offsets). x3/feat/gx/hseq overlap the (dead) x1
// region; wt/seg/whhT live past x2's end.
static constexpr size_t X1_OFF    = 0;          // 2048*32*400  = 26,214,400
static constexpr size_t X2_OFF    = 26214400;   // 2048*64*81   = 10,616,832
static constexpr size_t X3_OFF    = 0;          // 2048*64*49   =  6,422,528
static constexpr size_t FEAT_OFF  = 6422528;    // 2048*512     =  1,048,576
static constexpr size_t GX_OFF    = 7471104;    // 2048*1024    =  2,097,152
static constexpr size_t HSEQ_OFF  = 9568256;    // 2048*256     =    524,288
static constexpr size_t WT1_OFF   = 36831232;   // 256*32   = 8,192
static constexpr size_t WT2_OFF   = 36839424;   // 512*64   = 32,768
static constexpr size_t WT3_OFF   = 36872192;   // 576*64   = 36,864
static constexpr size_t WHT_OFF   = 36909056;   // 256*1024 = 262,144 (w_hh^T)
static constexpr size_t SEGT0_OFF = 37171200;   // int[2048]
static constexpr size_t SEGLEN_OFF= 37173248;   // int[2048]
static constexpr size_t SEGCNT_OFF= 37175296;   // int[16]

__device__ __forceinline__ float sigmoidf_(float x) {
  return 1.0f / (1.0f + __expf(-x));
}

// ---------------------------------------------------------------------------
// Prep: transpose conv weights to [patch][oc] and w_hh to [k][unit]
// ---------------------------------------------------------------------------
__global__ __launch_bounds__(256) void prep_kernel(
    const float* __restrict__ c1w, const float* __restrict__ c2w,
    const float* __restrict__ c3w, const float* __restrict__ whh,
    float* __restrict__ wt1, float* __restrict__ wt2,
    float* __restrict__ wt3, float* __restrict__ whhT) {
  int i = blockIdx.x * 256 + threadIdx.x;
  if (i < 8192) {                       // conv1: (32,256) -> (256,32)
    int p = i >> 5, oc = i & 31;
    wt1[i] = c1w[oc * 256 + p];
  } else if (i < 8192 + 32768) {        // conv2: (64,512) -> (512,64)
    int j = i - 8192; int p = j >> 6, oc = j & 63;
    wt2[j] = c2w[oc * 512 + p];
  } else if (i < 8192 + 32768 + 36864) {// conv3: (64,576) -> (576,64)
    int j = i - 40960; int p = j >> 6, oc = j & 63;
    wt3[j] = c3w[oc * 576 + p];
  } else if (i < 8192 + 32768 + 36864 + 262144) { // w_hh (1024,256)->(256,1024)
    int j = i - 77824; int kk = j >> 10, u = j & 1023;
    whhT[j] = whh[u * 256 + kk];
  }
}

// ---------------------------------------------------------------------------
// Segment planning: split each batch lane's 128 steps at episode starts.
// ---------------------------------------------------------------------------
__global__ __launch_bounds__(64) void plan_kernel(
    const float* __restrict__ starts, int* __restrict__ seg_t0,
    int* __restrict__ seg_len, int* __restrict__ seg_cnt) {
  int b = threadIdx.x;
  if (b >= 16) return;
  int base = b * 128;
  int cnt = 0;
  for (int t = 0; t < 128; ++t) {
    float s = starts[t * 16 + b];
    if (t == 0 || s != 0.0f) {
      if (cnt > 0) seg_len[base + cnt - 1] = t - seg_t0[base + cnt - 1];
      seg_t0[base + cnt] = t;
      ++cnt;
    }
  }
  seg_len[base + cnt - 1] = 128 - seg_t0[base + cnt - 1];
  seg_cnt[b] = cnt;
}

// ---------------------------------------------------------------------------
// conv1: (2048,4,84,84)/255 -> relu -> (2048,32,20,20); k=8 s=4
// One block per image; thread owns 2 spatial positions x all 32 oc.
// ---------------------------------------------------------------------------
__global__ __launch_bounds__(256) void conv1_kernel(
    const float* __restrict__ obs, const float* __restrict__ wt1,
    const float* __restrict__ b1, float* __restrict__ x1) {
  const int n = blockIdx.x;
  const int tid = threadIdx.x;
  __shared__ float wl[8192];  // 32 KB: [patch 256][oc 32]
  for (int i = tid; i < 8192; i += 256) wl[i] = wt1[i];
  __syncthreads();
  const int sp0 = tid, sp1 = tid + 256;
  const bool a1 = sp1 < 400;
  const int oy0 = sp0 / 20, ox0 = sp0 % 20;
  const int oy1 = sp1 / 20, ox1 = sp1 % 20;
  float acc0[32], acc1[32];
#pragma unroll
  for (int oc = 0; oc < 32; ++oc) { float bv = b1[oc]; acc0[oc] = bv; acc1[oc] = bv; }
  const float inv = 1.0f / 255.0f;
  const float* base = obs + (size_t)n * 28224;
  for (int ci = 0; ci < 4; ++ci) {
    for (int ky = 0; ky < 8; ++ky) {
      const float* r0 = base + (ci * 84 + oy0 * 4 + ky) * 84 + ox0 * 4;
      float xa[8], xb[8];
      {
        float4 p = *(const float4*)r0;
        float4 q = *(const float4*)(r0 + 4);
        xa[0]=p.x*inv; xa[1]=p.y*inv; xa[2]=p.z*inv; xa[3]=p.w*inv;
        xa[4]=q.x*inv; xa[5]=q.y*inv; xa[6]=q.z*inv; xa[7]=q.w*inv;
      }
      if (a1) {
        const float* r1 = base + (ci * 84 + oy1 * 4 + ky) * 84 + ox1 * 4;
        float4 p = *(const float4*)r1;
        float4 q = *(const float4*)(r1 + 4);
        xb[0]=p.x*inv; xb[1]=p.y*inv; xb[2]=p.z*inv; xb[3]=p.w*inv;
        xb[4]=q.x*inv; xb[5]=q.y*inv; xb[6]=q.z*inv; xb[7]=q.w*inv;
      } else {
#pragma unroll
        for (int i = 0; i < 8; ++i) xb[i] = 0.f;
      }
#pragma unroll
      for (int kx = 0; kx < 8; ++kx) {
        const int p = (ci * 64 + ky * 8 + kx) * 32;
        const float xv0 = xa[kx], xv1 = xb[kx];
#pragma unroll
        for (int o4 = 0; o4 < 8; ++o4) {
          const float4 w4 = *(const float4*)&wl[p + o4 * 4];
          acc0[o4*4+0] = fmaf(xv0, w4.x, acc0[o4*4+0]);
          acc0[o4*4+1] = fmaf(xv0, w4.y, acc0[o4*4+1]);
          acc0[o4*4+2] = fmaf(xv0, w4.z, acc0[o4*4+2]);
          acc0[o4*4+3] = fmaf(xv0, w4.w, acc0[o4*4+3]);
          acc1[o4*4+0] = fmaf(xv1, w4.x, acc1[o4*4+0]);
          acc1[o4*4+1] = fmaf(xv1, w4.y, acc1[o4*4+1]);
          acc1[o4*4+2] = fmaf(xv1, w4.z, acc1[o4*4+2]);
          acc1[o4*4+3] = fmaf(xv1, w4.w, acc1[o4*4+3]);
        }
      }
    }
  }
  float* out = x1 + (size_t)n * 12800;
#pragma unroll
  for (int oc = 0; oc < 32; ++oc) {
    out[oc * 400 + sp0] = fmaxf(acc0[oc], 0.f);
    if (a1) out[oc * 400 + sp1] = fmaxf(acc1[oc], 0.f);
  }
}

// ---------------------------------------------------------------------------
// conv2: (2048,32,20,20) -> relu -> (2048,64,9,9); k=4 s=2
// 3 images/block (243/256 lanes active), ci chunked by 4, inputs+weights in LDS
// ---------------------------------------------------------------------------
__global__ __launch_bounds__(256) void conv2_kernel(
    const float* __restrict__ x1, const float* __restrict__ wt2,
    const float* __restrict__ b2, float* __restrict__ x2) {
  const int nb = blockIdx.x * 3;
  const int tid = threadIdx.x;
  __shared__ float xs[3 * 1600];  // 19.2 KB
  __shared__ float wl[4096];      // 16 KB
  const int img = tid / 81;
  const int sp = tid - img * 81;
  const int n = nb + img;
  const bool act = (img < 3) && (n < 2048);
  const int oy = sp / 9, ox = sp - oy * 9;
  float acc[64];
#pragma unroll
  for (int oc = 0; oc < 64; ++oc) acc[oc] = b2[oc];
  for (int cc = 0; cc < 8; ++cc) {
    __syncthreads();
    {
      const float4* src = (const float4*)(wt2 + cc * 4096);
      float4* dst = (float4*)wl;
      for (int i = tid; i < 1024; i += 256) dst[i] = src[i];
    }
    for (int i = tid; i < 1200; i += 256) {
      const int im = i / 400;
      const int r4 = i - im * 400;
      const int n2 = nb + im;
      float4 v = make_float4(0.f, 0.f, 0.f, 0.f);
      if (n2 < 2048)
        v = *(const float4*)(x1 + (size_t)(n2 * 32 + cc * 4) * 400 + r4 * 4);
      ((float4*)xs)[im * 400 + r4] = v;
    }
    __syncthreads();
    if (act) {
      const float* xim = xs + img * 1600;
      for (int ci = 0; ci < 4; ++ci) {
#pragma unroll
        for (int ky = 0; ky < 4; ++ky) {
          const float* row = xim + ci * 400 + (oy * 2 + ky) * 20 + ox * 2;
          const float xv[4] = {row[0], row[1], row[2], row[3]};
#pragma unroll
          for (int kx = 0; kx < 4; ++kx) {
            const int p = (ci * 16 + ky * 4 + kx) * 64;
            const float xvv = xv[kx];
#pragma unroll
            for (int g = 0; g < 16; ++g) {
              const float4 w4 = *(const float4*)&wl[p + g * 4];
              acc[g*4+0] = fmaf(xvv, w4.x, acc[g*4+0]);
              acc[g*4+1] = fmaf(xvv, w4.y, acc[g*4+1]);
              acc[g*4+2] = fmaf(xvv, w4.z, acc[g*4+2]);
              acc[g*4+3] = fmaf(xvv, w4.w, acc[g*4+3]);
            }
          }
        }
      }
    }
  }
  if (act) {
    float* out = x2 + (size_t)n * 5184;
#pragma unroll
    for (int oc = 0; oc < 64; ++oc) out[oc * 81 + sp] = fmaxf(acc[oc], 0.f);
  }
}

// ---------------------------------------------------------------------------
// conv3: (2048,64,9,9) -> relu -> (2048,64,7,7); k=3 s=1
// 5 images/block (245/256 lanes active), ci chunked by 8
// ---------------------------------------------------------------------------
__global__ __launch_bounds__(256) void conv3_kernel(
    const float* __restrict__ x2, const float* __restrict__ wt3,
    const float* __restrict__ b3, float* __restrict__ x3) {
  const int nb = blockIdx.x * 5;
  const int tid = threadIdx.x;
  __shared__ float xs[5 * 648];   // 12.96 KB
  __shared__ float wl[4608];      // 18.4 KB
  const int img = tid / 49;
  const int sp = tid - img * 49;
  const int n = nb + img;
  const bool act = (img < 5) && (n < 2048);
  const int oy = sp / 7, ox = sp - oy * 7;
  float acc[64];
#pragma unroll
  for (int oc = 0; oc < 64; ++oc) acc[oc] = b3[oc];
  for (int cc = 0; cc < 8; ++cc) {
    __syncthreads();
    {
      const float4* src = (const float4*)(wt3 + cc * 4608);
      float4* dst = (float4*)wl;
      for (int i = tid; i < 1152; i += 256) dst[i] = src[i];
    }
    for (int i = tid; i < 3240; i += 256) {
      const int im = i / 648;
      const int r = i - im * 648;
      const int n2 = nb + im;
      float v = 0.f;
      if (n2 < 2048) v = x2[(size_t)(n2 * 64 + cc * 8) * 81 + r];
      xs[im * 648 + r] = v;
    }
    __syncthreads();
    if (act) {
      const float* xim = xs + img * 648;
      for (int ci = 0; ci < 8; ++ci) {
#pragma unroll
        for (int ky = 0; ky < 3; ++ky) {
          const float* row = xim + ci * 81 + (oy + ky) * 9 + ox;
          const float xv[3] = {row[0], row[1], row[2]};
#pragma unroll
          for (int kx = 0; kx < 3; ++kx) {
            const int p = (ci * 9 + ky * 3 + kx) * 64;
            const float xvv = xv[kx];
#pragma unroll
            for (int g = 0; g < 16; ++g) {
              const float4 w4 = *(const float4*)&wl[p + g * 4];
              acc[g*4+0] = fmaf(xvv, w4.x, acc[g*4+0]);
              acc[g*4+1] = fmaf(xvv, w4.y, acc[g*4+1]);
              acc[g*4+2] = fmaf(xvv, w4.z, acc[g*4+2]);
              acc[g*4+3] = fmaf(xvv, w4.w, acc[g*4+3]);
            }
          }
        }
      }
    }
  }
  if (act) {
    float* out = x3 + (size_t)n * 3136;
#pragma unroll
    for (int oc = 0; oc < 64; ++oc) out[oc * 49 + sp] = fmaxf(acc[oc], 0.f);
  }
}

// ---------------------------------------------------------------------------
// fp32 tiled GEMM: C[M,N] = act(A[M,K] @ W[N,K]^T + bias1 + bias2)
// 64x64 tile / block of 256, 4x4 per thread, K chunks of 32. M,N%64==0, K%32==0
// ---------------------------------------------------------------------------
__global__ __launch_bounds__(256) void gemm_nt_kernel(
    const float* __restrict__ A, const float* __restrict__ W,
    const float* __restrict__ bias1, const float* __restrict__ bias2,
    float* __restrict__ C, int M, int N, int K, int relu) {
  __shared__ float As[32][68];
  __shared__ float Bs[32][68];
  const int tid = threadIdx.x;
  const int m0 = blockIdx.y * 64, n0 = blockIdx.x * 64;
  const int ty = tid >> 4, tx = tid & 15;
  const int lr = tid >> 3, lc = tid & 7;
  float acc[4][4] = {};
  for (int k0 = 0; k0 < K; k0 += 32) {
    __syncthreads();
#pragma unroll
    for (int pass = 0; pass < 2; ++pass) {
      const int row = pass * 32 + lr;
      float4 av = *(const float4*)&A[(size_t)(m0 + row) * K + k0 + lc * 4];
      As[lc*4+0][row] = av.x; As[lc*4+1][row] = av.y;
      As[lc*4+2][row] = av.z; As[lc*4+3][row] = av.w;
      float4 bv = *(const float4*)&W[(size_t)(n0 + row) * K + k0 + lc * 4];
      Bs[lc*4+0][row] = bv.x; Bs[lc*4+1][row] = bv.y;
      Bs[lc*4+2][row] = bv.z; Bs[lc*4+3][row] = bv.w;
    }
    __syncthreads();
#pragma unroll
    for (int kk = 0; kk < 32; ++kk) {
      const float4 a4 = *(const float4*)&As[kk][ty * 4];
      const float4 b4 = *(const float4*)&Bs[kk][tx * 4];
      acc[0][0] = fmaf(a4.x, b4.x, acc[0][0]); acc[0][1] = fmaf(a4.x, b4.y, acc[0][1]);
      acc[0][2] = fmaf(a4.x, b4.z, acc[0][2]); acc[0][3] = fmaf(a4.x, b4.w, acc[0][3]);
      acc[1][0] = fmaf(a4.y, b4.x, acc[1][0]); acc[1][1] = fmaf(a4.y, b4.y, acc[1][1]);
      acc[1][2] = fmaf(a4.y, b4.z, acc[1][2]); acc[1][3] = fmaf(a4.y, b4.w, acc[1][3]);
      acc[2][0] = fmaf(a4.z, b4.x, acc[2][0]); acc[2][1] = fmaf(a4.z, b4.y, acc[2][1]);
      acc[2][2] = fmaf(a4.z, b4.z, acc[2][2]); acc[2][3] = fmaf(a4.z, b4.w, acc[2][3]);
      acc[3][0] = fmaf(a4.w, b4.x, acc[3][0]); acc[3][1] = fmaf(a4.w, b4.y, acc[3][1]);
      acc[3][2] = fmaf(a4.w, b4.z, acc[3][2]); acc[3][3] = fmaf(a4.w, b4.w, acc[3][3]);
    }
  }
  const int ncol = n0 + tx * 4;
  float bs[4];
#pragma unroll
  for (int j = 0; j < 4; ++j) {
    bs[j] = bias1[ncol + j] + (bias2 ? bias2[ncol + j] : 0.f);
  }
#pragma unroll
  for (int i = 0; i < 4; ++i) {
    const int mrow = m0 + ty * 4 + i;
    float4 o;
    o.x = acc[i][0] + bs[0]; o.y = acc[i][1] + bs[1];
    o.z = acc[i][2] + bs[2]; o.w = acc[i][3] + bs[3];
    if (relu) {
      o.x = fmaxf(o.x, 0.f); o.y = fmaxf(o.y, 0.f);
      o.z = fmaxf(o.z, 0.f); o.w = fmaxf(o.w, 0.f);
    }
    *(float4*)&C[(size_t)mrow * N + ncol] = o;
  }
}

// ---------------------------------------------------------------------------
// Segment-parallel LSTM. One block per (b, segment). Thread owns units
// 4*tid..4*tid+3 for the recurrent matvec (coalesced float4 w_hh^T loads),
// gates exchanged through LDS, thread j owns cell state c[j].
// ---------------------------------------------------------------------------
__global__ __launch_bounds__(256) void lstm_kernel(
    const float* __restrict__ gx, const float* __restrict__ whhT,
    const float* __restrict__ starts, const float* __restrict__ h0,
    const float* __restrict__ c0, const int* __restrict__ seg_t0,
    const int* __restrict__ seg_len, const int* __restrict__ seg_cnt,
    float* __restrict__ hseq) {
  const int slot = blockIdx.x;
  const int b = slot >> 7;
  const int k = slot & 127;
  if (k >= seg_cnt[b]) return;
  const int tid = threadIdx.x;
  const int t0 = seg_t0[slot];
  const int len = seg_len[slot];
  __shared__ float hs[256];
  __shared__ float pre[1024];
  float cj;
  if (t0 == 0) {
    const float keep0 = 1.0f - starts[b];  // starts[0*16+b]
    hs[tid] = h0[b * 256 + tid] * keep0;
    cj = c0[b * 256 + tid] * keep0;
  } else {
    hs[tid] = 0.f;  // segment start implies episode_start==1 -> state reset
    cj = 0.f;
  }
  __syncthreads();
  const float4* wT = (const float4*)whhT;  // [256 k][256 float4-units]
  for (int tt = 0; tt < len; ++tt) {
    const int t = t0 + tt;
    float4 acc = *(const float4*)&gx[(size_t)(t * 16 + b) * 1024 + 4 * tid];
    for (int kk = 0; kk < 256; kk += 4) {
      const float4 h4 = *(const float4*)&hs[kk];
      const float4 w0 = wT[(kk + 0) * 256 + tid];
      const float4 w1 = wT[(kk + 1) * 256 + tid];
      const float4 w2 = wT[(kk + 2) * 256 + tid];
      const float4 w3 = wT[(kk + 3) * 256 + tid];
      acc.x = fmaf(h4.x, w0.x, acc.x); acc.y = fmaf(h4.x, w0.y, acc.y);
      acc.z = fmaf(h4.x, w0.z, acc.z); acc.w = fmaf(h4.x, w0.w, acc.w);
      acc.x = fmaf(h4.y, w1.x, acc.x); acc.y = fmaf(h4.y, w1.y, acc.y);
      acc.z = fmaf(h4.y, w1.z, acc.z); acc.w = fmaf(h4.y, w1.w, acc.w);
      acc.x = fmaf(h4.z, w2.x, acc.x); acc.y = fmaf(h4.z, w2.y, acc.y);
      acc.z = fmaf(h4.z, w2.z, acc.z); acc.w = fmaf(h4.z, w2.w, acc.w);
      acc.x = fmaf(h4.w, w3.x, acc.x); acc.y = fmaf(h4.w, w3.y, acc.y);
      acc.z = fmaf(h4.w, w3.z, acc.z); acc.w = fmaf(h4.w, w3.w, acc.w);
    }
    *(float4*)&pre[4 * tid] = acc;
    __syncthreads();
    const float pi = pre[tid];
    const float pf = pre[256 + tid];
    const float pg = pre[512 + tid];
    const float po = pre[768 + tid];
    const float ii = sigmoidf_(pi);
    const float ff = sigmoidf_(pf);
    const float gg = tanhf(pg);
    const float oo = sigmoidf_(po);
    cj = fmaf(ff, cj, ii * gg);
    const float hj = oo * tanhf(cj);
    __syncthreads();
    hs[tid] = hj;
    hseq[(size_t)(t * 16 + b) * 256 + tid] = hj;
    __syncthreads();
  }
}

// ---------------------------------------------------------------------------
// aux head: aux_logits[tb] = feat[tb,:] . aux_w + aux_b  -> d_out[6144+tb]
// ---------------------------------------------------------------------------
__global__ __launch_bounds__(256) void aux_kernel(
    const float* __restrict__ feat, const float* __restrict__ aux_w,
    const float* __restrict__ aux_b, float* __restrict__ outp) {
  const int tb = blockIdx.x;
  const int tid = threadIdx.x;
  __shared__ float red[256];
  const float* f = feat + (size_t)tb * 512;
  red[tid] = f[tid] * aux_w[tid] + f[tid + 256] * aux_w[tid + 256];
  __syncthreads();
  for (int s = 128; s > 0; s >>= 1) {
    if (tid < s) red[tid] += red[tid + s];
    __syncthreads();
  }
  if (tid == 0) outp[6144 + tb] = red[0] + aux_b[0];
}

// ---------------------------------------------------------------------------
// actor/critic heads + log_softmax + gather + entropy
// ---------------------------------------------------------------------------
__global__ __launch_bounds__(64) void heads_kernel(
    const float* __restrict__ hseq, const int* __restrict__ actions,
    const float* __restrict__ actor_w, const float* __restrict__ actor_b,
    const float* __restrict__ critic_w, const float* __restrict__ critic_b,
    float* __restrict__ outp) {
  const int tb = blockIdx.x;
  const int tid = threadIdx.x;
  __shared__ float h[256];
  __shared__ float lg[32];
#pragma unroll
  for (int i = 0; i < 4; ++i) h[tid + 64 * i] = hseq[(size_t)tb * 256 + tid + 64 * i];
  __syncthreads();
  if (tid < 18) {
    float a = actor_b[tid];
    const float* w = actor_w + tid * 256;
    for (int kk = 0; kk < 256; ++kk) a = fmaf(h[kk], w[kk], a);
    lg[tid] = a;
  } else if (tid == 18) {
    float v = critic_b[0];
    for (int kk = 0; kk < 256; ++kk) v = fmaf(h[kk], critic_w[kk], v);
    lg[18] = v;
  }
  __syncthreads();
  if (tid == 0) {
    float m = -1e30f;
    for (int i = 0; i < 18; ++i) m = fmaxf(m, lg[i]);
    float se = 0.f;
    for (int i = 0; i < 18; ++i) se += expf(lg[i] - m);
    const float lse = logf(se);
    float ent = 0.f;
    for (int i = 0; i < 18; ++i) {
      const float lp = lg[i] - m - lse;
      ent -= expf(lp) * lp;
    }
    const int a = actions[tb];
    outp[tb] = lg[a] - m - lse;
    outp[2048 + tb] = ent;
    outp[4096 + tb] = lg[18];
  }
}

// ---------------------------------------------------------------------------
// launch
// ---------------------------------------------------------------------------
extern "C" void kernel_launch(void* const* d_in, const int* in_sizes, int n_in,
                              void* d_out, int out_size, void* d_ws, size_t ws_size,
                              hipStream_t stream) {
  const float* obs     = (const float*)d_in[0];
  const int*   actions = (const int*)d_in[1];
  const float* starts  = (const float*)d_in[2];
  const float* h0      = (const float*)d_in[3];
  const float* c0      = (const float*)d_in[4];
  const float* c1w     = (const float*)d_in[5];
  const float* c1b     = (const float*)d_in[6];
  const float* c2w     = (const float*)d_in[7];
  const float* c2b     = (const float*)d_in[8];
  const float* c3w     = (const float*)d_in[9];
  const float* c3b     = (const float*)d_in[10];
  const float* fcw     = (const float*)d_in[11];
  const float* fcb     = (const float*)d_in[12];
  const float* wih     = (const float*)d_in[13];
  const float* whh     = (const float*)d_in[14];
  const float* bih     = (const float*)d_in[15];
  const float* bhh     = (const float*)d_in[16];
  const float* aw      = (const float*)d_in[17];
  const float* ab      = (const float*)d_in[18];
  const float* cw      = (const float*)d_in[19];
  const float* cb      = (const float*)d_in[20];
  const float* auxw    = (const float*)d_in[21];
  const float* auxb    = (const float*)d_in[22];

  float* ws   = (float*)d_ws;
  float* x1   = ws + X1_OFF;
  float* x2   = ws + X2_OFF;
  float* x3   = ws + X3_OFF;
  float* feat = ws + FEAT_OFF;
  float* gx   = ws + GX_OFF;
  float* hseq = ws + HSEQ_OFF;
  float* wt1  = ws + WT1_OFF;
  float* wt2  = ws + WT2_OFF;
  float* wt3  = ws + WT3_OFF;
  float* whhT = ws + WHT_OFF;
  int* seg_t0  = (int*)(ws + SEGT0_OFF);
  int* seg_len = (int*)(ws + SEGLEN_OFF);
  int* seg_cnt = (int*)(ws + SEGCNT_OFF);
  float* outp  = (float*)d_out;

  prep_kernel<<<1328, 256, 0, stream>>>(c1w, c2w, c3w, whh, wt1, wt2, wt3, whhT);
  plan_kernel<<<1, 64, 0, stream>>>(starts, seg_t0, seg_len, seg_cnt);
  conv1_kernel<<<2048, 256, 0, stream>>>(obs, wt1, c1b, x1);
  conv2_kernel<<<683, 256, 0, stream>>>(x1, wt2, c2b, x2);
  conv3_kernel<<<410, 256, 0, stream>>>(x2, wt3, c3b, x3);
  gemm_nt_kernel<<<dim3(8, 32), 256, 0, stream>>>(x3, fcw, fcb, nullptr, feat,
                                                  2048, 512, 3136, 1);
  gemm_nt_kernel<<<dim3(16, 32), 256, 0, stream>>>(feat, wih, bih, bhh, gx,
                                                   2048, 1024, 512, 0);
  aux_kernel<<<2048, 256, 0, stream>>>(feat, auxw, auxb, outp);
  lstm_kernel<<<2048, 256, 0, stream>>>(gx, whhT, starts, h0, c0,
                                        seg_t0, seg_len, seg_cnt, hseq);
  heads_kernel<<<2048, 64, 0, stream>>>(hseq, actions, aw, ab, cw, cb, outp);
}

// Round 2
// 975.051 us; speedup vs baseline: 1.4370x; 1.4370x over previous
//
#include <hip/hip_runtime.h>
#include <hip/hip_bf16.h>
#include <cstddef>

typedef __attribute__((ext_vector_type(8))) short bf16x8;
typedef __attribute__((ext_vector_type(4))) float f32x4;

// ---------------------------------------------------------------------------
// Workspace byte offsets (total ~108.8 MB; R0 used 149 MB so ws_size is ample)
// ---------------------------------------------------------------------------
static constexpr size_t OFF_X1B   = 0;          // bf16 x1 CL [2048][20][20][32]
static constexpr size_t OFF_X2B   = 52428800;   // bf16 x2 CL [2048][9][9][64]
static constexpr size_t OFF_X3B   = 73662464;   // bf16 x3 rows [2048][3136] (sp*64+ci)
static constexpr size_t OFF_FEATB = 86507520;   // bf16 feat [2048][512]
static constexpr size_t OFF_W2B   = 88604672;   // bf16 [64][512]  k=(ky*4+kx)*32+ci
static constexpr size_t OFF_W3B   = 88670208;   // bf16 [64][576]  k=(ky*3+kx)*64+ci
static constexpr size_t OFF_FCWB  = 88743936;   // bf16 [512][3136] k=sp*64+ci
static constexpr size_t OFF_WIHB  = 91955200;   // bf16 [1024][512]
static constexpr size_t OFF_FEAT  = 93003776;   // f32 [2048][512]
static constexpr size_t OFF_GX    = 97198080;   // f32 [2048][1024]
static constexpr size_t OFF_HSEQ  = 105586688;  // f32 [2048][256]
static constexpr size_t OFF_WHHT  = 107683840;  // f32 [256][1024] w_hh^T
static constexpr size_t OFF_SEGT0 = 108732416;  // int[2048]
static constexpr size_t OFF_SEGLEN= 108740608;  // int[2048]
static constexpr size_t OFF_SEGCNT= 108748800;  // int[16]

__device__ __forceinline__ float sigmoidf_(float x) {
  return 1.0f / (1.0f + __expf(-x));
}

// ---------------------------------------------------------------------------
// Prep: bf16-convert + reorder weights; transpose w_hh
// ---------------------------------------------------------------------------
__global__ __launch_bounds__(256) void prep_kernel(
    const float* __restrict__ c2w, const float* __restrict__ c3w,
    const float* __restrict__ fcw, const float* __restrict__ wih,
    const float* __restrict__ whh,
    __hip_bfloat16* __restrict__ w2b, __hip_bfloat16* __restrict__ w3b,
    __hip_bfloat16* __restrict__ fcwb, __hip_bfloat16* __restrict__ wihb,
    float* __restrict__ whhT) {
  int i = blockIdx.x * 256 + threadIdx.x;
  if (i < 32768) {                          // w2b: k=(ky*4+kx)*32+ci
    int o = i >> 9, k = i & 511;
    int pos = k >> 5, ci = k & 31;
    int ky = pos >> 2, kx = pos & 3;
    w2b[i] = __float2bfloat16(c2w[o * 512 + ci * 16 + ky * 4 + kx]);
  } else if (i < 69632) {                   // w3b: k=(ky*3+kx)*64+ci
    int j = i - 32768;
    int o = j / 576, k = j - o * 576;
    int pos = k >> 6, ci = k & 63;
    int ky = pos / 3, kx = pos - ky * 3;
    w3b[j] = __float2bfloat16(c3w[o * 576 + ci * 9 + ky * 3 + kx]);
  } else if (i < 1675264) {                 // fcwb: k=sp*64+ci
    int j = i - 69632;
    int o = j / 3136, k = j - o * 3136;
    int sp = k >> 6, ci = k & 63;
    fcwb[j] = __float2bfloat16(fcw[o * 3136 + ci * 49 + sp]);
  } else if (i < 2199552) {                 // wihb: native
    int j = i - 1675264;
    wihb[j] = __float2bfloat16(wih[j]);
  } else if (i < 2461696) {                 // whhT (1024,256)->(256,1024)
    int j = i - 2199552;
    int kk = j >> 10, u = j & 1023;
    whhT[j] = whh[u * 256 + kk];
  }
}

// ---------------------------------------------------------------------------
// Segment planning
// ---------------------------------------------------------------------------
__global__ __launch_bounds__(64) void plan_kernel(
    const float* __restrict__ starts, int* __restrict__ seg_t0,
    int* __restrict__ seg_len, int* __restrict__ seg_cnt) {
  int b = threadIdx.x;
  if (b >= 16) return;
  int base = b * 128;
  int cnt = 0;
  for (int t = 0; t < 128; ++t) {
    float s = starts[t * 16 + b];
    if (t == 0 || s != 0.0f) {
      if (cnt > 0) seg_len[base + cnt - 1] = t - seg_t0[base + cnt - 1];
      seg_t0[base + cnt] = t;
      ++cnt;
    }
  }
  seg_len[base + cnt - 1] = 128 - seg_t0[base + cnt - 1];
  seg_cnt[b] = cnt;
}

// ---------------------------------------------------------------------------
// conv1: fp32 vector direct conv, writes x1 channels-last bf16 [n][20][20][32]
// ---------------------------------------------------------------------------
__global__ __launch_bounds__(256) void conv1_kernel(
    const float* __restrict__ obs, const float* __restrict__ wt1,
    const float* __restrict__ b1, __hip_bfloat16* __restrict__ x1b) {
  const int n = blockIdx.x;
  const int tid = threadIdx.x;
  __shared__ float wl[8192];  // [patch 256][oc 32]
  for (int i = tid; i < 8192; i += 256) wl[i] = wt1[i];
  __syncthreads();
  const int sp0 = tid, sp1 = tid + 256;
  const bool a1 = sp1 < 400;
  const int oy0 = sp0 / 20, ox0 = sp0 % 20;
  const int oy1 = sp1 / 20, ox1 = sp1 % 20;
  float acc0[32], acc1[32];
#pragma unroll
  for (int oc = 0; oc < 32; ++oc) { float bv = b1[oc]; acc0[oc] = bv; acc1[oc] = bv; }
  const float inv = 1.0f / 255.0f;
  const float* base = obs + (size_t)n * 28224;
  for (int ci = 0; ci < 4; ++ci) {
    for (int ky = 0; ky < 8; ++ky) {
      const float* r0 = base + (ci * 84 + oy0 * 4 + ky) * 84 + ox0 * 4;
      float xa[8], xb[8];
      {
        float4 p = *(const float4*)r0;
        float4 q = *(const float4*)(r0 + 4);
        xa[0]=p.x*inv; xa[1]=p.y*inv; xa[2]=p.z*inv; xa[3]=p.w*inv;
        xa[4]=q.x*inv; xa[5]=q.y*inv; xa[6]=q.z*inv; xa[7]=q.w*inv;
      }
      if (a1) {
        const float* r1 = base + (ci * 84 + oy1 * 4 + ky) * 84 + ox1 * 4;
        float4 p = *(const float4*)r1;
        float4 q = *(const float4*)(r1 + 4);
        xb[0]=p.x*inv; xb[1]=p.y*inv; xb[2]=p.z*inv; xb[3]=p.w*inv;
        xb[4]=q.x*inv; xb[5]=q.y*inv; xb[6]=q.z*inv; xb[7]=q.w*inv;
      } else {
#pragma unroll
        for (int i = 0; i < 8; ++i) xb[i] = 0.f;
      }
#pragma unroll
      for (int kx = 0; kx < 8; ++kx) {
        const int p = (ci * 64 + ky * 8 + kx) * 32;
        const float xv0 = xa[kx], xv1 = xb[kx];
#pragma unroll
        for (int o4 = 0; o4 < 8; ++o4) {
          const float4 w4 = *(const float4*)&wl[p + o4 * 4];
          acc0[o4*4+0] = fmaf(xv0, w4.x, acc0[o4*4+0]);
          acc0[o4*4+1] = fmaf(xv0, w4.y, acc0[o4*4+1]);
          acc0[o4*4+2] = fmaf(xv0, w4.z, acc0[o4*4+2]);
          acc0[o4*4+3] = fmaf(xv0, w4.w, acc0[o4*4+3]);
          acc1[o4*4+0] = fmaf(xv1, w4.x, acc1[o4*4+0]);
          acc1[o4*4+1] = fmaf(xv1, w4.y, acc1[o4*4+1]);
          acc1[o4*4+2] = fmaf(xv1, w4.z, acc1[o4*4+2]);
          acc1[o4*4+3] = fmaf(xv1, w4.w, acc1[o4*4+3]);
        }
      }
    }
  }
  // channels-last bf16 store: x1b[(n*400+sp)*32 + oc]
  __align__(16) unsigned short ob[32];
#pragma unroll
  for (int oc = 0; oc < 32; ++oc) {
    __hip_bfloat16 h = __float2bfloat16(fmaxf(acc0[oc], 0.f));
    ob[oc] = *(unsigned short*)&h;
  }
  unsigned short* o0 = (unsigned short*)x1b + ((size_t)n * 400 + sp0) * 32;
#pragma unroll
  for (int g = 0; g < 4; ++g) ((uint4*)o0)[g] = ((uint4*)ob)[g];
  if (a1) {
#pragma unroll
    for (int oc = 0; oc < 32; ++oc) {
      __hip_bfloat16 h = __float2bfloat16(fmaxf(acc1[oc], 0.f));
      ob[oc] = *(unsigned short*)&h;
    }
    unsigned short* o1 = (unsigned short*)x1b + ((size_t)n * 400 + sp1) * 32;
#pragma unroll
    for (int g = 0; g < 4; ++g) ((uint4*)o1)[g] = ((uint4*)ob)[g];
  }
}

// ---------------------------------------------------------------------------
// Unified bf16 MFMA NT-GEMM, BM x 64 tile, BK=32, 4 waves/block.
// MODE 0: A = plain [M][K] bf16 rows
// MODE 1: implicit im2col from x1 CL [n][20][20][32], k=(ky*4+kx)*32+ci, K=512
// MODE 2: implicit im2col from x2 CL [n][9][9][64],   k=(ky*3+kx)*64+ci, K=576
// C row m, col n:  D[row=(quad*4+r)][col=lane16] per 16x16 frag (m89/m91 map)
// ---------------------------------------------------------------------------
template<int BM, int MODE>
__global__ __launch_bounds__(256) void gemm_mfma(
    const __hip_bfloat16* __restrict__ Abase,
    const __hip_bfloat16* __restrict__ Wb,
    const float* __restrict__ bias1, const float* __restrict__ bias2,
    float* __restrict__ Cf, __hip_bfloat16* __restrict__ Cb,
    const int M, const int N, const int K, const int relu) {
  constexpr int LDK = 40;  // +8 bf16 pad: breaks pow-2 bank stride
  __shared__ __align__(16) __hip_bfloat16 As[BM * LDK];
  __shared__ __align__(16) __hip_bfloat16 Ws[64 * LDK];
  const int tid = threadIdx.x;
  const int m0 = blockIdx.y * BM;
  const int n0 = blockIdx.x * 64;
  const int l = tid & 63;
  const int wv = tid >> 6;
  const int lane16 = l & 15;
  const int quad = l >> 4;
  constexpr int NF = (BM == 128) ? 4 : 2;
  const int m_base = (BM == 128) ? wv * 32 : (wv & 1) * 32;
  const int n_base = (BM == 128) ? 0 : (wv >> 1) * 32;
  constexpr int NCA = (BM == 128) ? 2 : 1;  // A chunks per thread

  f32x4 acc[2][NF] = {};

  // Per-thread A staging descriptors (row fixed across K-loop)
  const __hip_bfloat16* arow[NCA];
  int acp[NCA];
#pragma unroll
  for (int c = 0; c < NCA; ++c) {
    const int id = tid + c * 256;
    const int row = id >> 2, cpos = id & 3;
    const int m = m0 + row;
    acp[c] = cpos;
    if (MODE == 0) {
      arow[c] = Abase + (size_t)m * K + cpos * 8;
    } else if (MODE == 1) {
      const int n = m / 81, sp = m - n * 81;
      const int oy = sp / 9, ox = sp - oy * 9;
      arow[c] = Abase + ((n * 20 + oy * 2) * 20 + ox * 2) * 32 + cpos * 8;
    } else {
      const int n = m / 49, sp = m - n * 49;
      const int oy = sp / 7, ox = sp - oy * 7;
      arow[c] = Abase + ((n * 9 + oy) * 9 + ox) * 64 + cpos * 8;
    }
  }
  const int wrow = tid >> 2, wcp = tid & 3;
  const __hip_bfloat16* wsrc = Wb + (size_t)(n0 + wrow) * K + wcp * 8;

  const int ksteps = K >> 5;
  for (int s = 0; s < ksteps; ++s) {
    uint4 av[NCA];
#pragma unroll
    for (int c = 0; c < NCA; ++c) {
      const __hip_bfloat16* p;
      if (MODE == 0) {
        p = arow[c] + s * 32;
      } else if (MODE == 1) {
        p = arow[c] + ((s >> 2) * 20 + (s & 3)) * 32;  // ky=s>>2, kx=s&3
      } else {
        const int pos = s >> 1;                        // ky*3+kx
        const int ky = pos / 3, kx = pos - ky * 3;
        p = arow[c] + (ky * 9 + kx) * 64 + (s & 1) * 32;
      }
      av[c] = *(const uint4*)p;
    }
    const uint4 wval = *(const uint4*)(wsrc + s * 32);
    __syncthreads();  // previous iter's frag reads done before overwrite
#pragma unroll
    for (int c = 0; c < NCA; ++c) {
      const int row = (tid + c * 256) >> 2;
      *(uint4*)&As[row * LDK + acp[c] * 8] = av[c];
    }
    *(uint4*)&Ws[wrow * LDK + wcp * 8] = wval;
    __syncthreads();
    const bf16x8 a0 = *(const bf16x8*)&As[(m_base + lane16) * LDK + quad * 8];
    const bf16x8 a1 = *(const bf16x8*)&As[(m_base + 16 + lane16) * LDK + quad * 8];
#pragma unroll
    for (int nf = 0; nf < NF; ++nf) {
      const bf16x8 b = *(const bf16x8*)&Ws[(n_base + nf * 16 + lane16) * LDK + quad * 8];
      acc[0][nf] = __builtin_amdgcn_mfma_f32_16x16x32_bf16(a0, b, acc[0][nf], 0, 0, 0);
      acc[1][nf] = __builtin_amdgcn_mfma_f32_16x16x32_bf16(a1, b, acc[1][nf], 0, 0, 0);
    }
  }
  // epilogue
#pragma unroll
  for (int nf = 0; nf < NF; ++nf) {
    const int col = n0 + n_base + nf * 16 + lane16;
    float bb = bias1[col];
    if (bias2) bb += bias2[col];
#pragma unroll
    for (int mf = 0; mf < 2; ++mf) {
#pragma unroll
      for (int r = 0; r < 4; ++r) {
        const int row = m0 + m_base + mf * 16 + quad * 4 + r;
        float v = acc[mf][nf][r] + bb;
        if (relu) v = fmaxf(v, 0.f);
        if (Cf) Cf[(size_t)row * N + col] = v;
        if (Cb) Cb[(size_t)row * N + col] = __float2bfloat16(v);
      }
    }
  }
}

// ---------------------------------------------------------------------------
// Segment-parallel LSTM (fp32). One block per (b, segment).
// ---------------------------------------------------------------------------
__global__ __launch_bounds__(256) void lstm_kernel(
    const float* __restrict__ gx, const float* __restrict__ whhT,
    const float* __restrict__ starts, const float* __restrict__ h0,
    const float* __restrict__ c0, const int* __restrict__ seg_t0,
    const int* __restrict__ seg_len, const int* __restrict__ seg_cnt,
    float* __restrict__ hseq) {
  const int slot = blockIdx.x;
  const int b = slot >> 7;
  const int k = slot & 127;
  if (k >= seg_cnt[b]) return;
  const int tid = threadIdx.x;
  const int t0 = seg_t0[slot];
  const int len = seg_len[slot];
  __shared__ float hs[256];
  __shared__ float pre[1024];
  float cj;
  if (t0 == 0) {
    const float keep0 = 1.0f - starts[b];
    hs[tid] = h0[b * 256 + tid] * keep0;
    cj = c0[b * 256 + tid] * keep0;
  } else {
    hs[tid] = 0.f;
    cj = 0.f;
  }
  __syncthreads();
  const float4* wT = (const float4*)whhT;  // [256 k][256 float4-units]
  for (int tt = 0; tt < len; ++tt) {
    const int t = t0 + tt;
    float4 acc = *(const float4*)&gx[(size_t)(t * 16 + b) * 1024 + 4 * tid];
    for (int kk = 0; kk < 256; kk += 4) {
      const float4 h4 = *(const float4*)&hs[kk];
      const float4 w0 = wT[(kk + 0) * 256 + tid];
      const float4 w1 = wT[(kk + 1) * 256 + tid];
      const float4 w2 = wT[(kk + 2) * 256 + tid];
      const float4 w3 = wT[(kk + 3) * 256 + tid];
      acc.x = fmaf(h4.x, w0.x, acc.x); acc.y = fmaf(h4.x, w0.y, acc.y);
      acc.z = fmaf(h4.x, w0.z, acc.z); acc.w = fmaf(h4.x, w0.w, acc.w);
      acc.x = fmaf(h4.y, w1.x, acc.x); acc.y = fmaf(h4.y, w1.y, acc.y);
      acc.z = fmaf(h4.y, w1.z, acc.z); acc.w = fmaf(h4.y, w1.w, acc.w);
      acc.x = fmaf(h4.z, w2.x, acc.x); acc.y = fmaf(h4.z, w2.y, acc.y);
      acc.z = fmaf(h4.z, w2.z, acc.z); acc.w = fmaf(h4.z, w2.w, acc.w);
      acc.x = fmaf(h4.w, w3.x, acc.x); acc.y = fmaf(h4.w, w3.y, acc.y);
      acc.z = fmaf(h4.w, w3.z, acc.z); acc.w = fmaf(h4.w, w3.w, acc.w);
    }
    *(float4*)&pre[4 * tid] = acc;
    __syncthreads();
    const float ii = sigmoidf_(pre[tid]);
    const float ff = sigmoidf_(pre[256 + tid]);
    const float gg = tanhf(pre[512 + tid]);
    const float oo = sigmoidf_(pre[768 + tid]);
    cj = fmaf(ff, cj, ii * gg);
    const float hj = oo * tanhf(cj);
    __syncthreads();
    hs[tid] = hj;
    hseq[(size_t)(t * 16 + b) * 256 + tid] = hj;
    __syncthreads();
  }
}

// ---------------------------------------------------------------------------
// aux head
// ---------------------------------------------------------------------------
__global__ __launch_bounds__(256) void aux_kernel(
    const float* __restrict__ feat, const float* __restrict__ aux_w,
    const float* __restrict__ aux_b, float* __restrict__ outp) {
  const int tb = blockIdx.x;
  const int tid = threadIdx.x;
  __shared__ float red[256];
  const float* f = feat + (size_t)tb * 512;
  red[tid] = f[tid] * aux_w[tid] + f[tid + 256] * aux_w[tid + 256];
  __syncthreads();
  for (int s = 128; s > 0; s >>= 1) {
    if (tid < s) red[tid] += red[tid + s];
    __syncthreads();
  }
  if (tid == 0) outp[6144 + tb] = red[0] + aux_b[0];
}

// ---------------------------------------------------------------------------
// actor/critic heads + log_softmax + gather + entropy
// ---------------------------------------------------------------------------
__global__ __launch_bounds__(64) void heads_kernel(
    const float* __restrict__ hseq, const int* __restrict__ actions,
    const float* __restrict__ actor_w, const float* __restrict__ actor_b,
    const float* __restrict__ critic_w, const float* __restrict__ critic_b,
    float* __restrict__ outp) {
  const int tb = blockIdx.x;
  const int tid = threadIdx.x;
  __shared__ float h[256];
  __shared__ float lg[32];
#pragma unroll
  for (int i = 0; i < 4; ++i) h[tid + 64 * i] = hseq[(size_t)tb * 256 + tid + 64 * i];
  __syncthreads();
  if (tid < 18) {
    float a = actor_b[tid];
    const float* w = actor_w + tid * 256;
    for (int kk = 0; kk < 256; ++kk) a = fmaf(h[kk], w[kk], a);
    lg[tid] = a;
  } else if (tid == 18) {
    float v = critic_b[0];
    for (int kk = 0; kk < 256; ++kk) v = fmaf(h[kk], critic_w[kk], v);
    lg[18] = v;
  }
  __syncthreads();
  if (tid == 0) {
    float m = -1e30f;
    for (int i = 0; i < 18; ++i) m = fmaxf(m, lg[i]);
    float se = 0.f;
    for (int i = 0; i < 18; ++i) se += expf(lg[i] - m);
    const float lse = logf(se);
    float ent = 0.f;
    for (int i = 0; i < 18; ++i) {
      const float lp = lg[i] - m - lse;
      ent -= expf(lp) * lp;
    }
    const int a = actions[tb];
    outp[tb] = lg[a] - m - lse;
    outp[2048 + tb] = ent;
    outp[4096 + tb] = lg[18];
  }
}

// conv1 weight transpose: (32,256) -> [patch 256][oc 32] fp32
__global__ __launch_bounds__(256) void prep1_kernel(
    const float* __restrict__ c1w, float* __restrict__ wt1) {
  int i = blockIdx.x * 256 + threadIdx.x;
  if (i < 8192) {
    int p = i >> 5, oc = i & 31;
    wt1[i] = c1w[oc * 256 + p];
  }
}

// ---------------------------------------------------------------------------
// launch
// ---------------------------------------------------------------------------
extern "C" void kernel_launch(void* const* d_in, const int* in_sizes, int n_in,
                              void* d_out, int out_size, void* d_ws, size_t ws_size,
                              hipStream_t stream) {
  const float* obs     = (const float*)d_in[0];
  const int*   actions = (const int*)d_in[1];
  const float* starts  = (const float*)d_in[2];
  const float* h0      = (const float*)d_in[3];
  const float* c0      = (const float*)d_in[4];
  const float* c1w     = (const float*)d_in[5];
  const float* c1b     = (const float*)d_in[6];
  const float* c2w     = (const float*)d_in[7];
  const float* c2b     = (const float*)d_in[8];
  const float* c3w     = (const float*)d_in[9];
  const float* c3b     = (const float*)d_in[10];
  const float* fcw     = (const float*)d_in[11];
  const float* fcb     = (const float*)d_in[12];
  const float* wih     = (const float*)d_in[13];
  const float* whh     = (const float*)d_in[14];
  const float* bih     = (const float*)d_in[15];
  const float* bhh     = (const float*)d_in[16];
  const float* aw      = (const float*)d_in[17];
  const float* ab      = (const float*)d_in[18];
  const float* cw      = (const float*)d_in[19];
  const float* cb      = (const float*)d_in[20];
  const float* auxw    = (const float*)d_in[21];
  const float* auxb    = (const float*)d_in[22];

  char* ws = (char*)d_ws;
  __hip_bfloat16* x1b   = (__hip_bfloat16*)(ws + OFF_X1B);
  __hip_bfloat16* x2b   = (__hip_bfloat16*)(ws + OFF_X2B);
  __hip_bfloat16* x3b   = (__hip_bfloat16*)(ws + OFF_X3B);
  __hip_bfloat16* featb = (__hip_bfloat16*)(ws + OFF_FEATB);
  __hip_bfloat16* w2b   = (__hip_bfloat16*)(ws + OFF_W2B);
  __hip_bfloat16* w3b   = (__hip_bfloat16*)(ws + OFF_W3B);
  __hip_bfloat16* fcwb  = (__hip_bfloat16*)(ws + OFF_FCWB);
  __hip_bfloat16* wihb  = (__hip_bfloat16*)(ws + OFF_WIHB);
  float* feat = (float*)(ws + OFF_FEAT);
  float* gx   = (float*)(ws + OFF_GX);
  float* hseq = (float*)(ws + OFF_HSEQ);
  float* whhT = (float*)(ws + OFF_WHHT);
  int* seg_t0  = (int*)(ws + OFF_SEGT0);
  int* seg_len = (int*)(ws + OFF_SEGLEN);
  int* seg_cnt = (int*)(ws + OFF_SEGCNT);
  // wt1 (fp32, 8192 floats) lives after SEGCNT
  float* wt1 = (float*)(ws + OFF_SEGCNT + 256);
  float* outp = (float*)d_out;

  prep_kernel<<<9617, 256, 0, stream>>>(c2w, c3w, fcw, wih, whh,
                                        w2b, w3b, fcwb, wihb, whhT);
  prep1_kernel<<<32, 256, 0, stream>>>(c1w, wt1);
  plan_kernel<<<1, 64, 0, stream>>>(starts, seg_t0, seg_len, seg_cnt);
  conv1_kernel<<<2048, 256, 0, stream>>>(obs, wt1, c1b, x1b);
  // conv2 as implicit-im2col MFMA GEMM: M=165888, N=64, K=512
  gemm_mfma<128, 1><<<dim3(1, 1296), 256, 0, stream>>>(
      x1b, w2b, c2b, nullptr, nullptr, x2b, 165888, 64, 512, 1);
  // conv3: M=100352, N=64, K=576
  gemm_mfma<128, 2><<<dim3(1, 784), 256, 0, stream>>>(
      x2b, w3b, c3b, nullptr, nullptr, x3b, 100352, 64, 576, 1);
  // fc: M=2048, N=512, K=3136 -> feat (f32) + featb (bf16)
  gemm_mfma<64, 0><<<dim3(8, 32), 256, 0, stream>>>(
      x3b, fcwb, fcb, nullptr, feat, featb, 2048, 512, 3136, 1);
  // gates-x: M=2048, N=1024, K=512 -> gx (f32), bias = bih + bhh
  gemm_mfma<64, 0><<<dim3(16, 32), 256, 0, stream>>>(
      featb, wihb, bih, bhh, gx, nullptr, 2048, 1024, 512, 0);
  aux_kernel<<<2048, 256, 0, stream>>>(feat, auxw, auxb, outp);
  lstm_kernel<<<2048, 256, 0, stream>>>(gx, whhT, starts, h0, c0,
                                        seg_t0, seg_len, seg_cnt, hseq);
  heads_kernel<<<2048, 64, 0, stream>>>(hseq, actions, aw, ab, cw, cb, outp);
}

// Round 3
// 880.731 us; speedup vs baseline: 1.5909x; 1.1071x over previous
//
#include <hip/hip_runtime.h>
#include <hip/hip_bf16.h>
#include <cstddef>

typedef __attribute__((ext_vector_type(8))) short bf16x8;
typedef __attribute__((ext_vector_type(4))) float f32x4;

// ---------------------------------------------------------------------------
// Workspace byte offsets
// ---------------------------------------------------------------------------
static constexpr size_t OFF_X1B   = 0;          // bf16 x1 CL [2048][20][20][32]
static constexpr size_t OFF_X2B   = 52428800;   // bf16 x2 CL [2048][9][9][64]
static constexpr size_t OFF_X3B   = 73662464;   // bf16 x3 rows [2048][3136] (sp*64+ci)
static constexpr size_t OFF_FEATB = 86507520;   // bf16 feat [2048][512]
static constexpr size_t OFF_W2B   = 88604672;   // bf16 [64][512]  k=(ky*4+kx)*32+ci
static constexpr size_t OFF_W3B   = 88670208;   // bf16 [64][576]  k=(ky*3+kx)*64+ci
static constexpr size_t OFF_FCWB  = 88743936;   // bf16 [512][3136] k=sp*64+ci
static constexpr size_t OFF_WIHB  = 91955200;   // bf16 [1024][512]
static constexpr size_t OFF_FEAT  = 93003776;   // f32 [2048][512]
static constexpr size_t OFF_GX    = 97198080;   // f32 [2048][1024]
static constexpr size_t OFF_HSEQ  = 105586688;  // f32 [2048][256]
static constexpr size_t OFF_WHHT  = 107683840;  // f32 [256][1024] w_hh^T
static constexpr size_t OFF_SEGT0 = 108732416;  // int[2048]
static constexpr size_t OFF_SEGLEN= 108740608;  // int[2048]
static constexpr size_t OFF_SEGCNT= 108748800;  // int[16]
static constexpr size_t OFF_W1B   = 108749056;  // bf16 [32][256] k=ky*32+ci*8+kx, pre-scaled by 1/255

__device__ __forceinline__ float sigmoidf_(float x) {
  return 1.0f / (1.0f + __expf(-x));
}

// ---------------------------------------------------------------------------
// Prep: bf16-convert + reorder weights; transpose w_hh; conv1 w (scaled 1/255)
// ---------------------------------------------------------------------------
__global__ __launch_bounds__(256) void prep_kernel(
    const float* __restrict__ c1w, const float* __restrict__ c2w,
    const float* __restrict__ c3w, const float* __restrict__ fcw,
    const float* __restrict__ wih, const float* __restrict__ whh,
    __hip_bfloat16* __restrict__ w1b,
    __hip_bfloat16* __restrict__ w2b, __hip_bfloat16* __restrict__ w3b,
    __hip_bfloat16* __restrict__ fcwb, __hip_bfloat16* __restrict__ wihb,
    float* __restrict__ whhT) {
  int i = blockIdx.x * 256 + threadIdx.x;
  if (i < 32768) {                          // w2b: k=(ky*4+kx)*32+ci
    int o = i >> 9, k = i & 511;
    int pos = k >> 5, ci = k & 31;
    int ky = pos >> 2, kx = pos & 3;
    w2b[i] = __float2bfloat16(c2w[o * 512 + ci * 16 + ky * 4 + kx]);
  } else if (i < 69632) {                   // w3b: k=(ky*3+kx)*64+ci
    int j = i - 32768;
    int o = j / 576, k = j - o * 576;
    int pos = k >> 6, ci = k & 63;
    int ky = pos / 3, kx = pos - ky * 3;
    w3b[j] = __float2bfloat16(c3w[o * 576 + ci * 9 + ky * 3 + kx]);
  } else if (i < 1675264) {                 // fcwb: k=sp*64+ci
    int j = i - 69632;
    int o = j / 3136, k = j - o * 3136;
    int sp = k >> 6, ci = k & 63;
    fcwb[j] = __float2bfloat16(fcw[o * 3136 + ci * 49 + sp]);
  } else if (i < 2199552) {                 // wihb: native
    int j = i - 1675264;
    wihb[j] = __float2bfloat16(wih[j]);
  } else if (i < 2461696) {                 // whhT (1024,256)->(256,1024)
    int j = i - 2199552;
    int kk = j >> 10, u = j & 1023;
    whhT[j] = whh[u * 256 + kk];
  } else if (i < 2469888) {                 // w1b: k=ky*32+ci*8+kx, *(1/255)
    int j = i - 2461696;
    int oc = j >> 8, k = j & 255;
    int ky = k >> 5, rem = k & 31;
    int ci = rem >> 3, kx = rem & 7;
    w1b[j] = __float2bfloat16(c1w[oc * 256 + ci * 64 + ky * 8 + kx] * (1.0f / 255.0f));
  }
}

// ---------------------------------------------------------------------------
// Segment planning
// ---------------------------------------------------------------------------
__global__ __launch_bounds__(64) void plan_kernel(
    const float* __restrict__ starts, int* __restrict__ seg_t0,
    int* __restrict__ seg_len, int* __restrict__ seg_cnt) {
  int b = threadIdx.x;
  if (b >= 16) return;
  int base = b * 128;
  int cnt = 0;
  for (int t = 0; t < 128; ++t) {
    float s = starts[t * 16 + b];
    if (t == 0 || s != 0.0f) {
      if (cnt > 0) seg_len[base + cnt - 1] = t - seg_t0[base + cnt - 1];
      seg_t0[base + cnt] = t;
      ++cnt;
    }
  }
  seg_len[base + cnt - 1] = 128 - seg_t0[base + cnt - 1];
  seg_cnt[b] = cnt;
}

// ---------------------------------------------------------------------------
// conv1 as implicit-im2col bf16 MFMA GEMM.
// M=819200 (n*400+sp), N=32, K=256 with k = ky*32 + ci*8 + kx  ->  each 8-k
// chunk is 8 consecutive x-pixels of obs[n][ci][oy*4+ky][ox*4..+7] (NCHW raw).
// A-stager converts fp32->bf16 in-register (weights pre-scaled by 1/255).
// Output: x1b channels-last [n][20][20][32].
// ---------------------------------------------------------------------------
__global__ __launch_bounds__(256) void conv1_mfma(
    const float* __restrict__ obs, const __hip_bfloat16* __restrict__ w1b,
    const float* __restrict__ b1, __hip_bfloat16* __restrict__ x1b) {
  constexpr int LDK = 40;
  __shared__ __align__(16) __hip_bfloat16 As[128 * LDK];
  __shared__ __align__(16) __hip_bfloat16 Ws[32 * LDK];
  const int tid = threadIdx.x;
  const int m0 = blockIdx.x * 128;
  const int l = tid & 63;
  const int wv = tid >> 6;
  const int lane16 = l & 15;
  const int quad = l >> 4;
  const int m_base = wv * 32;

  f32x4 acc[2][2] = {};

  // A staging: 512 chunks (128 rows x 4), 2 per thread. cpos = ci.
  const float* arow[2];
  int arw[2], acp[2];
#pragma unroll
  for (int c = 0; c < 2; ++c) {
    const int id = tid + c * 256;
    const int row = id >> 2, cpos = id & 3;
    arw[c] = row; acp[c] = cpos;
    const int m = m0 + row;
    const int n = m / 400, sp = m - n * 400;
    const int oy = sp / 20, ox = sp - oy * 20;
    arow[c] = obs + (size_t)n * 28224 + cpos * 7056 + (oy * 4) * 84 + ox * 4;
  }
  // W staging: 128 chunks, threads 0..127
  const int wrow = tid >> 2, wcp = tid & 3;
  const __hip_bfloat16* wsrc = w1b + wrow * 256 + wcp * 8;

  for (int s = 0; s < 8; ++s) {  // s = ky
    float4 p[2], q[2];
#pragma unroll
    for (int c = 0; c < 2; ++c) {
      const float* r = arow[c] + s * 84;
      p[c] = *(const float4*)r;
      q[c] = *(const float4*)(r + 4);
    }
    uint4 wval;
    if (tid < 128) wval = *(const uint4*)(wsrc + s * 32);
    __syncthreads();
#pragma unroll
    for (int c = 0; c < 2; ++c) {
      __hip_bfloat16* d = &As[arw[c] * LDK + acp[c] * 8];
      d[0] = __float2bfloat16(p[c].x); d[1] = __float2bfloat16(p[c].y);
      d[2] = __float2bfloat16(p[c].z); d[3] = __float2bfloat16(p[c].w);
      d[4] = __float2bfloat16(q[c].x); d[5] = __float2bfloat16(q[c].y);
      d[6] = __float2bfloat16(q[c].z); d[7] = __float2bfloat16(q[c].w);
    }
    if (tid < 128) *(uint4*)&Ws[wrow * LDK + wcp * 8] = wval;
    __syncthreads();
    const bf16x8 a0 = *(const bf16x8*)&As[(m_base + lane16) * LDK + quad * 8];
    const bf16x8 a1 = *(const bf16x8*)&As[(m_base + 16 + lane16) * LDK + quad * 8];
#pragma unroll
    for (int nf = 0; nf < 2; ++nf) {
      const bf16x8 b = *(const bf16x8*)&Ws[(nf * 16 + lane16) * LDK + quad * 8];
      acc[0][nf] = __builtin_amdgcn_mfma_f32_16x16x32_bf16(a0, b, acc[0][nf], 0, 0, 0);
      acc[1][nf] = __builtin_amdgcn_mfma_f32_16x16x32_bf16(a1, b, acc[1][nf], 0, 0, 0);
    }
  }
#pragma unroll
  for (int nf = 0; nf < 2; ++nf) {
    const int col = nf * 16 + lane16;
    const float bb = b1[col];
#pragma unroll
    for (int mf = 0; mf < 2; ++mf) {
#pragma unroll
      for (int r = 0; r < 4; ++r) {
        const int row = m0 + m_base + mf * 16 + quad * 4 + r;
        const float v = fmaxf(acc[mf][nf][r] + bb, 0.f);
        x1b[(size_t)row * 32 + col] = __float2bfloat16(v);
      }
    }
  }
}

// ---------------------------------------------------------------------------
// Unified bf16 MFMA NT-GEMM, BM x 64 tile, BK=32, 4 waves/block.
// MODE 0: A = plain [M][K] bf16 rows
// MODE 1: implicit im2col from x1 CL [n][20][20][32], k=(ky*4+kx)*32+ci, K=512
// MODE 2: implicit im2col from x2 CL [n][9][9][64],   k=(ky*3+kx)*64+ci, K=576
// ---------------------------------------------------------------------------
template<int BM, int MODE>
__global__ __launch_bounds__(256) void gemm_mfma(
    const __hip_bfloat16* __restrict__ Abase,
    const __hip_bfloat16* __restrict__ Wb,
    const float* __restrict__ bias1, const float* __restrict__ bias2,
    float* __restrict__ Cf, __hip_bfloat16* __restrict__ Cb,
    const int M, const int N, const int K, const int relu) {
  constexpr int LDK = 40;
  __shared__ __align__(16) __hip_bfloat16 As[BM * LDK];
  __shared__ __align__(16) __hip_bfloat16 Ws[64 * LDK];
  const int tid = threadIdx.x;
  const int m0 = blockIdx.y * BM;
  const int n0 = blockIdx.x * 64;
  const int l = tid & 63;
  const int wv = tid >> 6;
  const int lane16 = l & 15;
  const int quad = l >> 4;
  constexpr int NF = (BM == 128) ? 4 : 2;
  const int m_base = (BM == 128) ? wv * 32 : (wv & 1) * 32;
  const int n_base = (BM == 128) ? 0 : (wv >> 1) * 32;
  constexpr int NCA = (BM == 128) ? 2 : 1;

  f32x4 acc[2][NF] = {};

  const __hip_bfloat16* arow[NCA];
  int acp[NCA];
#pragma unroll
  for (int c = 0; c < NCA; ++c) {
    const int id = tid + c * 256;
    const int row = id >> 2, cpos = id & 3;
    const int m = m0 + row;
    acp[c] = cpos;
    if (MODE == 0) {
      arow[c] = Abase + (size_t)m * K + cpos * 8;
    } else if (MODE == 1) {
      const int n = m / 81, sp = m - n * 81;
      const int oy = sp / 9, ox = sp - oy * 9;
      arow[c] = Abase + ((n * 20 + oy * 2) * 20 + ox * 2) * 32 + cpos * 8;
    } else {
      const int n = m / 49, sp = m - n * 49;
      const int oy = sp / 7, ox = sp - oy * 7;
      arow[c] = Abase + ((n * 9 + oy) * 9 + ox) * 64 + cpos * 8;
    }
  }
  const int wrow = tid >> 2, wcp = tid & 3;
  const __hip_bfloat16* wsrc = Wb + (size_t)(n0 + wrow) * K + wcp * 8;

  const int ksteps = K >> 5;
  for (int s = 0; s < ksteps; ++s) {
    uint4 av[NCA];
#pragma unroll
    for (int c = 0; c < NCA; ++c) {
      const __hip_bfloat16* p;
      if (MODE == 0) {
        p = arow[c] + s * 32;
      } else if (MODE == 1) {
        p = arow[c] + ((s >> 2) * 20 + (s & 3)) * 32;
      } else {
        const int pos = s >> 1;
        const int ky = pos / 3, kx = pos - ky * 3;
        p = arow[c] + (ky * 9 + kx) * 64 + (s & 1) * 32;
      }
      av[c] = *(const uint4*)p;
    }
    const uint4 wval = *(const uint4*)(wsrc + s * 32);
    __syncthreads();
#pragma unroll
    for (int c = 0; c < NCA; ++c) {
      const int row = (tid + c * 256) >> 2;
      *(uint4*)&As[row * LDK + acp[c] * 8] = av[c];
    }
    *(uint4*)&Ws[wrow * LDK + wcp * 8] = wval;
    __syncthreads();
    const bf16x8 a0 = *(const bf16x8*)&As[(m_base + lane16) * LDK + quad * 8];
    const bf16x8 a1 = *(const bf16x8*)&As[(m_base + 16 + lane16) * LDK + quad * 8];
#pragma unroll
    for (int nf = 0; nf < NF; ++nf) {
      const bf16x8 b = *(const bf16x8*)&Ws[(n_base + nf * 16 + lane16) * LDK + quad * 8];
      acc[0][nf] = __builtin_amdgcn_mfma_f32_16x16x32_bf16(a0, b, acc[0][nf], 0, 0, 0);
      acc[1][nf] = __builtin_amdgcn_mfma_f32_16x16x32_bf16(a1, b, acc[1][nf], 0, 0, 0);
    }
  }
#pragma unroll
  for (int nf = 0; nf < NF; ++nf) {
    const int col = n0 + n_base + nf * 16 + lane16;
    float bb = bias1[col];
    if (bias2) bb += bias2[col];
#pragma unroll
    for (int mf = 0; mf < 2; ++mf) {
#pragma unroll
      for (int r = 0; r < 4; ++r) {
        const int row = m0 + m_base + mf * 16 + quad * 4 + r;
        float v = acc[mf][nf][r] + bb;
        if (relu) v = fmaxf(v, 0.f);
        if (Cf) Cf[(size_t)row * N + col] = v;
        if (Cb) Cb[(size_t)row * N + col] = __float2bfloat16(v);
      }
    }
  }
}

// ---------------------------------------------------------------------------
// Segment-parallel LSTM (fp32). One block per (b, segment).
// ---------------------------------------------------------------------------
__global__ __launch_bounds__(256) void lstm_kernel(
    const float* __restrict__ gx, const float* __restrict__ whhT,
    const float* __restrict__ starts, const float* __restrict__ h0,
    const float* __restrict__ c0, const int* __restrict__ seg_t0,
    const int* __restrict__ seg_len, const int* __restrict__ seg_cnt,
    float* __restrict__ hseq) {
  const int slot = blockIdx.x;
  const int b = slot >> 7;
  const int k = slot & 127;
  if (k >= seg_cnt[b]) return;
  const int tid = threadIdx.x;
  const int t0 = seg_t0[slot];
  const int len = seg_len[slot];
  __shared__ float hs[256];
  __shared__ float pre[1024];
  float cj;
  if (t0 == 0) {
    const float keep0 = 1.0f - starts[b];
    hs[tid] = h0[b * 256 + tid] * keep0;
    cj = c0[b * 256 + tid] * keep0;
  } else {
    hs[tid] = 0.f;
    cj = 0.f;
  }
  __syncthreads();
  const float4* wT = (const float4*)whhT;
  for (int tt = 0; tt < len; ++tt) {
    const int t = t0 + tt;
    float4 acc = *(const float4*)&gx[(size_t)(t * 16 + b) * 1024 + 4 * tid];
    for (int kk = 0; kk < 256; kk += 4) {
      const float4 h4 = *(const float4*)&hs[kk];
      const float4 w0 = wT[(kk + 0) * 256 + tid];
      const float4 w1 = wT[(kk + 1) * 256 + tid];
      const float4 w2 = wT[(kk + 2) * 256 + tid];
      const float4 w3 = wT[(kk + 3) * 256 + tid];
      acc.x = fmaf(h4.x, w0.x, acc.x); acc.y = fmaf(h4.x, w0.y, acc.y);
      acc.z = fmaf(h4.x, w0.z, acc.z); acc.w = fmaf(h4.x, w0.w, acc.w);
      acc.x = fmaf(h4.y, w1.x, acc.x); acc.y = fmaf(h4.y, w1.y, acc.y);
      acc.z = fmaf(h4.y, w1.z, acc.z); acc.w = fmaf(h4.y, w1.w, acc.w);
      acc.x = fmaf(h4.z, w2.x, acc.x); acc.y = fmaf(h4.z, w2.y, acc.y);
      acc.z = fmaf(h4.z, w2.z, acc.z); acc.w = fmaf(h4.z, w2.w, acc.w);
      acc.x = fmaf(h4.w, w3.x, acc.x); acc.y = fmaf(h4.w, w3.y, acc.y);
      acc.z = fmaf(h4.w, w3.z, acc.z); acc.w = fmaf(h4.w, w3.w, acc.w);
    }
    *(float4*)&pre[4 * tid] = acc;
    __syncthreads();
    const float ii = sigmoidf_(pre[tid]);
    const float ff = sigmoidf_(pre[256 + tid]);
    const float gg = tanhf(pre[512 + tid]);
    const float oo = sigmoidf_(pre[768 + tid]);
    cj = fmaf(ff, cj, ii * gg);
    const float hj = oo * tanhf(cj);
    __syncthreads();
    hs[tid] = hj;
    hseq[(size_t)(t * 16 + b) * 256 + tid] = hj;
    __syncthreads();
  }
}

// ---------------------------------------------------------------------------
// aux head
// ---------------------------------------------------------------------------
__global__ __launch_bounds__(256) void aux_kernel(
    const float* __restrict__ feat, const float* __restrict__ aux_w,
    const float* __restrict__ aux_b, float* __restrict__ outp) {
  const int tb = blockIdx.x;
  const int tid = threadIdx.x;
  __shared__ float red[256];
  const float* f = feat + (size_t)tb * 512;
  red[tid] = f[tid] * aux_w[tid] + f[tid + 256] * aux_w[tid + 256];
  __syncthreads();
  for (int s = 128; s > 0; s >>= 1) {
    if (tid < s) red[tid] += red[tid + s];
    __syncthreads();
  }
  if (tid == 0) outp[6144 + tb] = red[0] + aux_b[0];
}

// ---------------------------------------------------------------------------
// actor/critic heads + log_softmax + gather + entropy
// ---------------------------------------------------------------------------
__global__ __launch_bounds__(64) void heads_kernel(
    const float* __restrict__ hseq, const int* __restrict__ actions,
    const float* __restrict__ actor_w, const float* __restrict__ actor_b,
    const float* __restrict__ critic_w, const float* __restrict__ critic_b,
    float* __restrict__ outp) {
  const int tb = blockIdx.x;
  const int tid = threadIdx.x;
  __shared__ float h[256];
  __shared__ float lg[32];
#pragma unroll
  for (int i = 0; i < 4; ++i) h[tid + 64 * i] = hseq[(size_t)tb * 256 + tid + 64 * i];
  __syncthreads();
  if (tid < 18) {
    float a = actor_b[tid];
    const float* w = actor_w + tid * 256;
    for (int kk = 0; kk < 256; ++kk) a = fmaf(h[kk], w[kk], a);
    lg[tid] = a;
  } else if (tid == 18) {
    float v = critic_b[0];
    for (int kk = 0; kk < 256; ++kk) v = fmaf(h[kk], critic_w[kk], v);
    lg[18] = v;
  }
  __syncthreads();
  if (tid == 0) {
    float m = -1e30f;
    for (int i = 0; i < 18; ++i) m = fmaxf(m, lg[i]);
    float se = 0.f;
    for (int i = 0; i < 18; ++i) se += expf(lg[i] - m);
    const float lse = logf(se);
    float ent = 0.f;
    for (int i = 0; i < 18; ++i) {
      const float lp = lg[i] - m - lse;
      ent -= expf(lp) * lp;
    }
    const int a = actions[tb];
    outp[tb] = lg[a] - m - lse;
    outp[2048 + tb] = ent;
    outp[4096 + tb] = lg[18];
  }
}

// ---------------------------------------------------------------------------
// launch
// ---------------------------------------------------------------------------
extern "C" void kernel_launch(void* const* d_in, const int* in_sizes, int n_in,
                              void* d_out, int out_size, void* d_ws, size_t ws_size,
                              hipStream_t stream) {
  const float* obs     = (const float*)d_in[0];
  const int*   actions = (const int*)d_in[1];
  const float* starts  = (const float*)d_in[2];
  const float* h0      = (const float*)d_in[3];
  const float* c0      = (const float*)d_in[4];
  const float* c1w     = (const float*)d_in[5];
  const float* c1b     = (const float*)d_in[6];
  const float* c2w     = (const float*)d_in[7];
  const float* c2b     = (const float*)d_in[8];
  const float* c3w     = (const float*)d_in[9];
  const float* c3b     = (const float*)d_in[10];
  const float* fcw     = (const float*)d_in[11];
  const float* fcb     = (const float*)d_in[12];
  const float* wih     = (const float*)d_in[13];
  const float* whh     = (const float*)d_in[14];
  const float* bih     = (const float*)d_in[15];
  const float* bhh     = (const float*)d_in[16];
  const float* aw      = (const float*)d_in[17];
  const float* ab      = (const float*)d_in[18];
  const float* cw      = (const float*)d_in[19];
  const float* cb      = (const float*)d_in[20];
  const float* auxw    = (const float*)d_in[21];
  const float* auxb    = (const float*)d_in[22];

  char* ws = (char*)d_ws;
  __hip_bfloat16* x1b   = (__hip_bfloat16*)(ws + OFF_X1B);
  __hip_bfloat16* x2b   = (__hip_bfloat16*)(ws + OFF_X2B);
  __hip_bfloat16* x3b   = (__hip_bfloat16*)(ws + OFF_X3B);
  __hip_bfloat16* featb = (__hip_bfloat16*)(ws + OFF_FEATB);
  __hip_bfloat16* w2b   = (__hip_bfloat16*)(ws + OFF_W2B);
  __hip_bfloat16* w3b   = (__hip_bfloat16*)(ws + OFF_W3B);
  __hip_bfloat16* fcwb  = (__hip_bfloat16*)(ws + OFF_FCWB);
  __hip_bfloat16* wihb  = (__hip_bfloat16*)(ws + OFF_WIHB);
  __hip_bfloat16* w1b   = (__hip_bfloat16*)(ws + OFF_W1B);
  float* feat = (float*)(ws + OFF_FEAT);
  float* gx   = (float*)(ws + OFF_GX);
  float* hseq = (float*)(ws + OFF_HSEQ);
  float* whhT = (float*)(ws + OFF_WHHT);
  int* seg_t0  = (int*)(ws + OFF_SEGT0);
  int* seg_len = (int*)(ws + OFF_SEGLEN);
  int* seg_cnt = (int*)(ws + OFF_SEGCNT);
  float* outp = (float*)d_out;

  prep_kernel<<<9648, 256, 0, stream>>>(c1w, c2w, c3w, fcw, wih, whh,
                                        w1b, w2b, w3b, fcwb, wihb, whhT);
  plan_kernel<<<1, 64, 0, stream>>>(starts, seg_t0, seg_len, seg_cnt);
  // conv1 as implicit-im2col MFMA: M=819200, N=32, K=256
  conv1_mfma<<<6400, 256, 0, stream>>>(obs, w1b, c1b, x1b);
  // conv2: M=165888, N=64, K=512
  gemm_mfma<128, 1><<<dim3(1, 1296), 256, 0, stream>>>(
      x1b, w2b, c2b, nullptr, nullptr, x2b, 165888, 64, 512, 1);
  // conv3: M=100352, N=64, K=576
  gemm_mfma<128, 2><<<dim3(1, 784), 256, 0, stream>>>(
      x2b, w3b, c3b, nullptr, nullptr, x3b, 100352, 64, 576, 1);
  // fc: M=2048, N=512, K=3136 -> feat (f32) + featb (bf16)
  gemm_mfma<64, 0><<<dim3(8, 32), 256, 0, stream>>>(
      x3b, fcwb, fcb, nullptr, feat, featb, 2048, 512, 3136, 1);
  // gates-x: M=2048, N=1024, K=512 -> gx (f32), bias = bih + bhh
  gemm_mfma<64, 0><<<dim3(16, 32), 256, 0, stream>>>(
      featb, wihb, bih, bhh, gx, nullptr, 2048, 1024, 512, 0);
  aux_kernel<<<2048, 256, 0, stream>>>(feat, auxw, auxb, outp);
  lstm_kernel<<<2048, 256, 0, stream>>>(gx, whhT, starts, h0, c0,
                                        seg_t0, seg_len, seg_cnt, hseq);
  heads_kernel<<<2048, 64, 0, stream>>>(hseq, actions, aw, ab, cw, cb, outp);
}

// Round 4
// 798.527 us; speedup vs baseline: 1.7547x; 1.1029x over previous
//
#include <hip/hip_runtime.h>
#include <hip/hip_bf16.h>
#include <cstddef>

typedef __attribute__((ext_vector_type(8))) short bf16x8;
typedef __attribute__((ext_vector_type(4))) float f32x4;

// ---------------------------------------------------------------------------
// Workspace byte offsets
// ---------------------------------------------------------------------------
static constexpr size_t OFF_X1B   = 0;          // bf16 x1 CL [2048][20][20][32]
static constexpr size_t OFF_X2B   = 52428800;   // bf16 x2 CL [2048][9][9][64]
static constexpr size_t OFF_X3B   = 73662464;   // bf16 x3 rows [2048][3136]
static constexpr size_t OFF_FEATB = 86507520;   // bf16 feat [2048][512]
static constexpr size_t OFF_W2B   = 88604672;   // bf16 [64][512]
static constexpr size_t OFF_W3B   = 88670208;   // bf16 [64][576]
static constexpr size_t OFF_FCWB  = 88743936;   // bf16 [512][3136]
static constexpr size_t OFF_WIHB  = 91955200;   // bf16 [1024][512]
static constexpr size_t OFF_FEAT  = 93003776;   // f32 [2048][512]
static constexpr size_t OFF_GX    = 97198080;   // f32 [2048][1024]
static constexpr size_t OFF_HSEQ  = 105586688;  // f32 [2048][256]
static constexpr size_t OFF_W1B   = 108732416;  // bf16 [32][256]
static constexpr size_t OFF_WHHB  = 108748800;  // bf16 [1024][256] straight copy
static constexpr size_t OFF_ORDB  = 109273088;  // int[2048]
static constexpr size_t OFF_ORDT0 = 109281280;  // int[2048]
static constexpr size_t OFF_ORDLEN= 109289472;  // int[2048]
static constexpr size_t OFF_NSEG  = 109297664;  // int[1]

__device__ __forceinline__ float sigmoidf_(float x) {
  return 1.0f / (1.0f + __expf(-x));
}

// ---------------------------------------------------------------------------
// Prep: bf16-convert + reorder weights
// ---------------------------------------------------------------------------
__global__ __launch_bounds__(256) void prep_kernel(
    const float* __restrict__ c1w, const float* __restrict__ c2w,
    const float* __restrict__ c3w, const float* __restrict__ fcw,
    const float* __restrict__ wih, const float* __restrict__ whh,
    __hip_bfloat16* __restrict__ w1b,
    __hip_bfloat16* __restrict__ w2b, __hip_bfloat16* __restrict__ w3b,
    __hip_bfloat16* __restrict__ fcwb, __hip_bfloat16* __restrict__ wihb,
    __hip_bfloat16* __restrict__ whhb) {
  int i = blockIdx.x * 256 + threadIdx.x;
  if (i < 32768) {                          // w2b: k=(ky*4+kx)*32+ci
    int o = i >> 9, k = i & 511;
    int pos = k >> 5, ci = k & 31;
    int ky = pos >> 2, kx = pos & 3;
    w2b[i] = __float2bfloat16(c2w[o * 512 + ci * 16 + ky * 4 + kx]);
  } else if (i < 69632) {                   // w3b: k=(ky*3+kx)*64+ci
    int j = i - 32768;
    int o = j / 576, k = j - o * 576;
    int pos = k >> 6, ci = k & 63;
    int ky = pos / 3, kx = pos - ky * 3;
    w3b[j] = __float2bfloat16(c3w[o * 576 + ci * 9 + ky * 3 + kx]);
  } else if (i < 1675264) {                 // fcwb: k=sp*64+ci
    int j = i - 69632;
    int o = j / 3136, k = j - o * 3136;
    int sp = k >> 6, ci = k & 63;
    fcwb[j] = __float2bfloat16(fcw[o * 3136 + ci * 49 + sp]);
  } else if (i < 2199552) {                 // wihb: native
    int j = i - 1675264;
    wihb[j] = __float2bfloat16(wih[j]);
  } else if (i < 2461696) {                 // whhb: straight bf16 copy [1024][256]
    int j = i - 2199552;
    whhb[j] = __float2bfloat16(whh[j]);
  } else if (i < 2469888) {                 // w1b: k=ky*32+ci*8+kx, *(1/255)
    int j = i - 2461696;
    int oc = j >> 8, k = j & 255;
    int ky = k >> 5, rem = k & 31;
    int ci = rem >> 3, kx = rem & 7;
    w1b[j] = __float2bfloat16(c1w[oc * 256 + ci * 64 + ky * 8 + kx] * (1.0f / 255.0f));
  }
}

// ---------------------------------------------------------------------------
// Segment planning: extract segments per b, counting-sort by length desc,
// emit ord_b/ord_t0/ord_len (groups of 16 -> one lstm block each).
// ---------------------------------------------------------------------------
__global__ __launch_bounds__(256) void plan_kernel(
    const float* __restrict__ starts, int* __restrict__ ord_b,
    int* __restrict__ ord_t0, int* __restrict__ ord_len,
    int* __restrict__ nseg_out) {
  __shared__ int s_t0[2048];
  __shared__ int s_len[2048];
  __shared__ int cnt[16];
  __shared__ int hist[132];
  __shared__ int off[132];
  const int tid = threadIdx.x;
  if (tid < 16) {
    int b = tid, c = 0;
    for (int t = 0; t < 128; ++t) {
      float s = starts[t * 16 + b];
      if (t == 0 || s != 0.0f) {
        if (c > 0) s_len[b * 128 + c - 1] = t - s_t0[b * 128 + c - 1];
        s_t0[b * 128 + c] = t;
        ++c;
      }
    }
    s_len[b * 128 + c - 1] = 128 - s_t0[b * 128 + c - 1];
    cnt[b] = c;
  }
  if (tid < 132) hist[tid] = 0;
  __syncthreads();
  for (int idx = tid; idx < 2048; idx += 256) {
    int b = idx >> 7, i = idx & 127;
    if (i < cnt[b]) atomicAdd(&hist[s_len[idx]], 1);
  }
  __syncthreads();
  if (tid == 0) {
    int running = 0;
    for (int L = 128; L >= 1; --L) { off[L] = running; running += hist[L]; }
    *nseg_out = running;
  }
  __syncthreads();
  for (int idx = tid; idx < 2048; idx += 256) {
    int b = idx >> 7, i = idx & 127;
    if (i < cnt[b]) {
      int len = s_len[idx];
      int pos = atomicAdd(&off[len], 1);
      ord_b[pos] = b;
      ord_t0[pos] = s_t0[idx];
      ord_len[pos] = len;
    }
  }
}

// ---------------------------------------------------------------------------
// conv1 as implicit-im2col bf16 MFMA GEMM. M=819200, N=32, K=256.
// ---------------------------------------------------------------------------
__global__ __launch_bounds__(256) void conv1_mfma(
    const float* __restrict__ obs, const __hip_bfloat16* __restrict__ w1b,
    const float* __restrict__ b1, __hip_bfloat16* __restrict__ x1b) {
  constexpr int LDK = 40;
  __shared__ __align__(16) __hip_bfloat16 As[128 * LDK];
  __shared__ __align__(16) __hip_bfloat16 Ws[32 * LDK];
  const int tid = threadIdx.x;
  const int m0 = blockIdx.x * 128;
  const int l = tid & 63;
  const int wv = tid >> 6;
  const int lane16 = l & 15;
  const int quad = l >> 4;
  const int m_base = wv * 32;

  f32x4 acc[2][2] = {};

  const float* arow[2];
  int arw[2], acp[2];
#pragma unroll
  for (int c = 0; c < 2; ++c) {
    const int id = tid + c * 256;
    const int row = id >> 2, cpos = id & 3;
    arw[c] = row; acp[c] = cpos;
    const int m = m0 + row;
    const int n = m / 400, sp = m - n * 400;
    const int oy = sp / 20, ox = sp - oy * 20;
    arow[c] = obs + (size_t)n * 28224 + cpos * 7056 + (oy * 4) * 84 + ox * 4;
  }
  const int wrow = tid >> 2, wcp = tid & 3;
  const __hip_bfloat16* wsrc = w1b + wrow * 256 + wcp * 8;

  for (int s = 0; s < 8; ++s) {
    float4 p[2], q[2];
#pragma unroll
    for (int c = 0; c < 2; ++c) {
      const float* r = arow[c] + s * 84;
      p[c] = *(const float4*)r;
      q[c] = *(const float4*)(r + 4);
    }
    uint4 wval;
    if (tid < 128) wval = *(const uint4*)(wsrc + s * 32);
    __syncthreads();
#pragma unroll
    for (int c = 0; c < 2; ++c) {
      __hip_bfloat16* d = &As[arw[c] * LDK + acp[c] * 8];
      d[0] = __float2bfloat16(p[c].x); d[1] = __float2bfloat16(p[c].y);
      d[2] = __float2bfloat16(p[c].z); d[3] = __float2bfloat16(p[c].w);
      d[4] = __float2bfloat16(q[c].x); d[5] = __float2bfloat16(q[c].y);
      d[6] = __float2bfloat16(q[c].z); d[7] = __float2bfloat16(q[c].w);
    }
    if (tid < 128) *(uint4*)&Ws[wrow * LDK + wcp * 8] = wval;
    __syncthreads();
    const bf16x8 a0 = *(const bf16x8*)&As[(m_base + lane16) * LDK + quad * 8];
    const bf16x8 a1 = *(const bf16x8*)&As[(m_base + 16 + lane16) * LDK + quad * 8];
#pragma unroll
    for (int nf = 0; nf < 2; ++nf) {
      const bf16x8 b = *(const bf16x8*)&Ws[(nf * 16 + lane16) * LDK + quad * 8];
      acc[0][nf] = __builtin_amdgcn_mfma_f32_16x16x32_bf16(a0, b, acc[0][nf], 0, 0, 0);
      acc[1][nf] = __builtin_amdgcn_mfma_f32_16x16x32_bf16(a1, b, acc[1][nf], 0, 0, 0);
    }
  }
#pragma unroll
  for (int nf = 0; nf < 2; ++nf) {
    const int col = nf * 16 + lane16;
    const float bb = b1[col];
#pragma unroll
    for (int mf = 0; mf < 2; ++mf) {
#pragma unroll
      for (int r = 0; r < 4; ++r) {
        const int row = m0 + m_base + mf * 16 + quad * 4 + r;
        const float v = fmaxf(acc[mf][nf][r] + bb, 0.f);
        x1b[(size_t)row * 32 + col] = __float2bfloat16(v);
      }
    }
  }
}

// ---------------------------------------------------------------------------
// Unified bf16 MFMA NT-GEMM (same as R2)
// ---------------------------------------------------------------------------
template<int BM, int MODE>
__global__ __launch_bounds__(256) void gemm_mfma(
    const __hip_bfloat16* __restrict__ Abase,
    const __hip_bfloat16* __restrict__ Wb,
    const float* __restrict__ bias1, const float* __restrict__ bias2,
    float* __restrict__ Cf, __hip_bfloat16* __restrict__ Cb,
    const int M, const int N, const int K, const int relu) {
  constexpr int LDK = 40;
  __shared__ __align__(16) __hip_bfloat16 As[BM * LDK];
  __shared__ __align__(16) __hip_bfloat16 Ws[64 * LDK];
  const int tid = threadIdx.x;
  const int m0 = blockIdx.y * BM;
  const int n0 = blockIdx.x * 64;
  const int l = tid & 63;
  const int wv = tid >> 6;
  const int lane16 = l & 15;
  const int quad = l >> 4;
  constexpr int NF = (BM == 128) ? 4 : 2;
  const int m_base = (BM == 128) ? wv * 32 : (wv & 1) * 32;
  const int n_base = (BM == 128) ? 0 : (wv >> 1) * 32;
  constexpr int NCA = (BM == 128) ? 2 : 1;

  f32x4 acc[2][NF] = {};

  const __hip_bfloat16* arow[NCA];
  int acp[NCA];
#pragma unroll
  for (int c = 0; c < NCA; ++c) {
    const int id = tid + c * 256;
    const int row = id >> 2, cpos = id & 3;
    const int m = m0 + row;
    acp[c] = cpos;
    if (MODE == 0) {
      arow[c] = Abase + (size_t)m * K + cpos * 8;
    } else if (MODE == 1) {
      const int n = m / 81, sp = m - n * 81;
      const int oy = sp / 9, ox = sp - oy * 9;
      arow[c] = Abase + ((n * 20 + oy * 2) * 20 + ox * 2) * 32 + cpos * 8;
    } else {
      const int n = m / 49, sp = m - n * 49;
      const int oy = sp / 7, ox = sp - oy * 7;
      arow[c] = Abase + ((n * 9 + oy) * 9 + ox) * 64 + cpos * 8;
    }
  }
  const int wrow = tid >> 2, wcp = tid & 3;
  const __hip_bfloat16* wsrc = Wb + (size_t)(n0 + wrow) * K + wcp * 8;

  const int ksteps = K >> 5;
  for (int s = 0; s < ksteps; ++s) {
    uint4 av[NCA];
#pragma unroll
    for (int c = 0; c < NCA; ++c) {
      const __hip_bfloat16* p;
      if (MODE == 0) {
        p = arow[c] + s * 32;
      } else if (MODE == 1) {
        p = arow[c] + ((s >> 2) * 20 + (s & 3)) * 32;
      } else {
        const int pos = s >> 1;
        const int ky = pos / 3, kx = pos - ky * 3;
        p = arow[c] + (ky * 9 + kx) * 64 + (s & 1) * 32;
      }
      av[c] = *(const uint4*)p;
    }
    const uint4 wval = *(const uint4*)(wsrc + s * 32);
    __syncthreads();
#pragma unroll
    for (int c = 0; c < NCA; ++c) {
      const int row = (tid + c * 256) >> 2;
      *(uint4*)&As[row * LDK + acp[c] * 8] = av[c];
    }
    *(uint4*)&Ws[wrow * LDK + wcp * 8] = wval;
    __syncthreads();
    const bf16x8 a0 = *(const bf16x8*)&As[(m_base + lane16) * LDK + quad * 8];
    const bf16x8 a1 = *(const bf16x8*)&As[(m_base + 16 + lane16) * LDK + quad * 8];
#pragma unroll
    for (int nf = 0; nf < NF; ++nf) {
      const bf16x8 b = *(const bf16x8*)&Ws[(n_base + nf * 16 + lane16) * LDK + quad * 8];
      acc[0][nf] = __builtin_amdgcn_mfma_f32_16x16x32_bf16(a0, b, acc[0][nf], 0, 0, 0);
      acc[1][nf] = __builtin_amdgcn_mfma_f32_16x16x32_bf16(a1, b, acc[1][nf], 0, 0, 0);
    }
  }
#pragma unroll
  for (int nf = 0; nf < NF; ++nf) {
    const int col = n0 + n_base + nf * 16 + lane16;
    float bb = bias1[col];
    if (bias2) bb += bias2[col];
#pragma unroll
    for (int mf = 0; mf < 2; ++mf) {
#pragma unroll
      for (int r = 0; r < 4; ++r) {
        const int row = m0 + m_base + mf * 16 + quad * 4 + r;
        float v = acc[mf][nf][r] + bb;
        if (relu) v = fmaxf(v, 0.f);
        if (Cf) Cf[(size_t)row * N + col] = v;
        if (Cb) Cb[(size_t)row * N + col] = __float2bfloat16(v);
      }
    }
  }
}

// ---------------------------------------------------------------------------
// Grouped-segment MFMA LSTM. One block = 1024 threads = 16 waves handles 16
// segments (M=16). Wave w pins B-frags (w_hh cols [64w,64w+64)) in VGPRs —
// zero weight traffic per step. h: LDS bf16; pre-activations: LDS f32;
// cell state: registers. Per step: [16x256]@[256x1024] via 32 MFMA/wave.
// ---------------------------------------------------------------------------
__global__ __launch_bounds__(1024, 4) void lstm_mfma(
    const float* __restrict__ gx, const __hip_bfloat16* __restrict__ whhb,
    const float* __restrict__ starts, const float* __restrict__ h0,
    const float* __restrict__ c0, const int* __restrict__ ord_b,
    const int* __restrict__ ord_t0, const int* __restrict__ ord_len,
    const int* __restrict__ nseg_p, float* __restrict__ hseq) {
  constexpr int LDH = 264;   // bf16 row stride (256+8): 2-way bank alias only
  constexpr int PS  = 1028;  // f32 row stride (1024+4)
  __shared__ __align__(16) __hip_bfloat16 h_lds[16 * LDH];
  __shared__ __align__(16) float pre[16 * PS];
  __shared__ int sg_b[16], sg_t0[16], sg_len[16];
  const int g = blockIdx.x;
  const int nseg = *nseg_p;
  if (g * 16 >= nseg) return;
  const int tid = threadIdx.x;
  const int wv = tid >> 6;      // 0..15
  const int l = tid & 63;
  const int lane16 = l & 15, quad = l >> 4;
  if (tid < 16) {
    const int s = g * 16 + tid;
    sg_b[tid] = (s < nseg) ? ord_b[s] : 0;
    sg_t0[tid] = (s < nseg) ? ord_t0[s] : 0;
    sg_len[tid] = (s < nseg) ? ord_len[s] : 0;
  }
  __syncthreads();
  // B fragments: wave wv owns gate-cols [wv*64, wv*64+64)
  bf16x8 bfrag[4][8];
#pragma unroll
  for (int nt = 0; nt < 4; ++nt)
#pragma unroll
    for (int ks = 0; ks < 8; ++ks)
      bfrag[nt][ks] = *(const bf16x8*)&whhb[
          (size_t)(wv * 64 + nt * 16 + lane16) * 256 + ks * 32 + quad * 8];
  // update-phase ownership: wave wv == segment slot wv; thread owns units u..u+3
  const int m_own = wv;
  const int u = l * 4;
  const int b_own = sg_b[m_own];
  const int t0_own = sg_t0[m_own];
  const int len_own = sg_len[m_own];
  float4 c_reg = make_float4(0.f, 0.f, 0.f, 0.f);
  {
    float4 hv = make_float4(0.f, 0.f, 0.f, 0.f);
    if (len_own > 0 && t0_own == 0) {
      const float keep = 1.0f - starts[b_own];
      const float4 h4 = *(const float4*)&h0[b_own * 256 + u];
      const float4 c4 = *(const float4*)&c0[b_own * 256 + u];
      hv = make_float4(h4.x * keep, h4.y * keep, h4.z * keep, h4.w * keep);
      c_reg = make_float4(c4.x * keep, c4.y * keep, c4.z * keep, c4.w * keep);
    }
    __hip_bfloat16* hd = &h_lds[m_own * LDH + u];
    hd[0] = __float2bfloat16(hv.x); hd[1] = __float2bfloat16(hv.y);
    hd[2] = __float2bfloat16(hv.z); hd[3] = __float2bfloat16(hv.w);
  }
  const int maxlen = sg_len[0];  // sorted desc within group
  for (int tt = 0; tt < maxlen; ++tt) {
    __syncthreads();  // h_lds ready
    // gx prefetch (update layout)
    const bool act = tt < len_own;
    const int t = t0_own + tt;
    const size_t gbase = act ? ((size_t)(t * 16 + b_own) * 1024 + u) : 0;
    const float4 g0 = *(const float4*)&gx[gbase];
    const float4 g1 = *(const float4*)&gx[gbase + 256];
    const float4 g2 = *(const float4*)&gx[gbase + 512];
    const float4 g3 = *(const float4*)&gx[gbase + 768];
    // A frags from h_lds
    bf16x8 afr[8];
#pragma unroll
    for (int ks = 0; ks < 8; ++ks)
      afr[ks] = *(const bf16x8*)&h_lds[lane16 * LDH + ks * 32 + quad * 8];
    f32x4 acc[4] = {};
#pragma unroll
    for (int nt = 0; nt < 4; ++nt)
#pragma unroll
      for (int ks = 0; ks < 8; ++ks)
        acc[nt] = __builtin_amdgcn_mfma_f32_16x16x32_bf16(
            afr[ks], bfrag[nt][ks], acc[nt], 0, 0, 0);
    // scatter pre-activations: D[m=quad*4+r][n=wv*64+nt*16+lane16]
#pragma unroll
    for (int nt = 0; nt < 4; ++nt)
#pragma unroll
      for (int r = 0; r < 4; ++r)
        pre[(quad * 4 + r) * PS + wv * 64 + nt * 16 + lane16] = acc[nt][r];
    __syncthreads();
    if (act) {
      const float4 p0 = *(const float4*)&pre[m_own * PS + u];
      const float4 p1 = *(const float4*)&pre[m_own * PS + u + 256];
      const float4 p2 = *(const float4*)&pre[m_own * PS + u + 512];
      const float4 p3 = *(const float4*)&pre[m_own * PS + u + 768];
      const float i0 = sigmoidf_(p0.x + g0.x), i1 = sigmoidf_(p0.y + g0.y),
                  i2 = sigmoidf_(p0.z + g0.z), i3 = sigmoidf_(p0.w + g0.w);
      const float f0 = sigmoidf_(p1.x + g1.x), f1 = sigmoidf_(p1.y + g1.y),
                  f2 = sigmoidf_(p1.z + g1.z), f3 = sigmoidf_(p1.w + g1.w);
      const float q0 = tanhf(p2.x + g2.x), q1 = tanhf(p2.y + g2.y),
                  q2 = tanhf(p2.z + g2.z), q3 = tanhf(p2.w + g2.w);
      const float o0 = sigmoidf_(p3.x + g3.x), o1 = sigmoidf_(p3.y + g3.y),
                  o2 = sigmoidf_(p3.z + g3.z), o3 = sigmoidf_(p3.w + g3.w);
      c_reg.x = fmaf(f0, c_reg.x, i0 * q0);
      c_reg.y = fmaf(f1, c_reg.y, i1 * q1);
      c_reg.z = fmaf(f2, c_reg.z, i2 * q2);
      c_reg.w = fmaf(f3, c_reg.w, i3 * q3);
      const float4 h4 = make_float4(o0 * tanhf(c_reg.x), o1 * tanhf(c_reg.y),
                                    o2 * tanhf(c_reg.z), o3 * tanhf(c_reg.w));
      __hip_bfloat16* hd = &h_lds[m_own * LDH + u];
      hd[0] = __float2bfloat16(h4.x); hd[1] = __float2bfloat16(h4.y);
      hd[2] = __float2bfloat16(h4.z); hd[3] = __float2bfloat16(h4.w);
      *(float4*)&hseq[(size_t)(t * 16 + b_own) * 256 + u] = h4;
    }
  }
}

// ---------------------------------------------------------------------------
// aux head
// ---------------------------------------------------------------------------
__global__ __launch_bounds__(256) void aux_kernel(
    const float* __restrict__ feat, const float* __restrict__ aux_w,
    const float* __restrict__ aux_b, float* __restrict__ outp) {
  const int tb = blockIdx.x;
  const int tid = threadIdx.x;
  __shared__ float red[256];
  const float* f = feat + (size_t)tb * 512;
  red[tid] = f[tid] * aux_w[tid] + f[tid + 256] * aux_w[tid + 256];
  __syncthreads();
  for (int s = 128; s > 0; s >>= 1) {
    if (tid < s) red[tid] += red[tid + s];
    __syncthreads();
  }
  if (tid == 0) outp[6144 + tb] = red[0] + aux_b[0];
}

// ---------------------------------------------------------------------------
// actor/critic heads + log_softmax + gather + entropy
// ---------------------------------------------------------------------------
__global__ __launch_bounds__(64) void heads_kernel(
    const float* __restrict__ hseq, const int* __restrict__ actions,
    const float* __restrict__ actor_w, const float* __restrict__ actor_b,
    const float* __restrict__ critic_w, const float* __restrict__ critic_b,
    float* __restrict__ outp) {
  const int tb = blockIdx.x;
  const int tid = threadIdx.x;
  __shared__ float h[256];
  __shared__ float lg[32];
#pragma unroll
  for (int i = 0; i < 4; ++i) h[tid + 64 * i] = hseq[(size_t)tb * 256 + tid + 64 * i];
  __syncthreads();
  if (tid < 18) {
    float a = actor_b[tid];
    const float* w = actor_w + tid * 256;
    for (int kk = 0; kk < 256; ++kk) a = fmaf(h[kk], w[kk], a);
    lg[tid] = a;
  } else if (tid == 18) {
    float v = critic_b[0];
    for (int kk = 0; kk < 256; ++kk) v = fmaf(h[kk], critic_w[kk], v);
    lg[18] = v;
  }
  __syncthreads();
  if (tid == 0) {
    float m = -1e30f;
    for (int i = 0; i < 18; ++i) m = fmaxf(m, lg[i]);
    float se = 0.f;
    for (int i = 0; i < 18; ++i) se += expf(lg[i] - m);
    const float lse = logf(se);
    float ent = 0.f;
    for (int i = 0; i < 18; ++i) {
      const float lp = lg[i] - m - lse;
      ent -= expf(lp) * lp;
    }
    const int a = actions[tb];
    outp[tb] = lg[a] - m - lse;
    outp[2048 + tb] = ent;
    outp[4096 + tb] = lg[18];
  }
}

// ---------------------------------------------------------------------------
// launch
// ---------------------------------------------------------------------------
extern "C" void kernel_launch(void* const* d_in, const int* in_sizes, int n_in,
                              void* d_out, int out_size, void* d_ws, size_t ws_size,
                              hipStream_t stream) {
  const float* obs     = (const float*)d_in[0];
  const int*   actions = (const int*)d_in[1];
  const float* starts  = (const float*)d_in[2];
  const float* h0      = (const float*)d_in[3];
  const float* c0      = (const float*)d_in[4];
  const float* c1w     = (const float*)d_in[5];
  const float* c1b     = (const float*)d_in[6];
  const float* c2w     = (const float*)d_in[7];
  const float* c2b     = (const float*)d_in[8];
  const float* c3w     = (const float*)d_in[9];
  const float* c3b     = (const float*)d_in[10];
  const float* fcw     = (const float*)d_in[11];
  const float* fcb     = (const float*)d_in[12];
  const float* wih     = (const float*)d_in[13];
  const float* whh     = (const float*)d_in[14];
  const float* bih     = (const float*)d_in[15];
  const float* bhh     = (const float*)d_in[16];
  const float* aw      = (const float*)d_in[17];
  const float* ab      = (const float*)d_in[18];
  const float* cw      = (const float*)d_in[19];
  const float* cb      = (const float*)d_in[20];
  const float* auxw    = (const float*)d_in[21];
  const float* auxb    = (const float*)d_in[22];

  char* ws = (char*)d_ws;
  __hip_bfloat16* x1b   = (__hip_bfloat16*)(ws + OFF_X1B);
  __hip_bfloat16* x2b   = (__hip_bfloat16*)(ws + OFF_X2B);
  __hip_bfloat16* x3b   = (__hip_bfloat16*)(ws + OFF_X3B);
  __hip_bfloat16* featb = (__hip_bfloat16*)(ws + OFF_FEATB);
  __hip_bfloat16* w2b   = (__hip_bfloat16*)(ws + OFF_W2B);
  __hip_bfloat16* w3b   = (__hip_bfloat16*)(ws + OFF_W3B);
  __hip_bfloat16* fcwb  = (__hip_bfloat16*)(ws + OFF_FCWB);
  __hip_bfloat16* wihb  = (__hip_bfloat16*)(ws + OFF_WIHB);
  __hip_bfloat16* w1b   = (__hip_bfloat16*)(ws + OFF_W1B);
  __hip_bfloat16* whhb  = (__hip_bfloat16*)(ws + OFF_WHHB);
  float* feat = (float*)(ws + OFF_FEAT);
  float* gx   = (float*)(ws + OFF_GX);
  float* hseq = (float*)(ws + OFF_HSEQ);
  int* ord_b   = (int*)(ws + OFF_ORDB);
  int* ord_t0  = (int*)(ws + OFF_ORDT0);
  int* ord_len = (int*)(ws + OFF_ORDLEN);
  int* nseg    = (int*)(ws + OFF_NSEG);
  float* outp = (float*)d_out;

  prep_kernel<<<9648, 256, 0, stream>>>(c1w, c2w, c3w, fcw, wih, whh,
                                        w1b, w2b, w3b, fcwb, wihb, whhb);
  plan_kernel<<<1, 256, 0, stream>>>(starts, ord_b, ord_t0, ord_len, nseg);
  conv1_mfma<<<6400, 256, 0, stream>>>(obs, w1b, c1b, x1b);
  gemm_mfma<128, 1><<<dim3(1, 1296), 256, 0, stream>>>(
      x1b, w2b, c2b, nullptr, nullptr, x2b, 165888, 64, 512, 1);
  gemm_mfma<128, 2><<<dim3(1, 784), 256, 0, stream>>>(
      x2b, w3b, c3b, nullptr, nullptr, x3b, 100352, 64, 576, 1);
  gemm_mfma<64, 0><<<dim3(8, 32), 256, 0, stream>>>(
      x3b, fcwb, fcb, nullptr, feat, featb, 2048, 512, 3136, 1);
  gemm_mfma<64, 0><<<dim3(16, 32), 256, 0, stream>>>(
      featb, wihb, bih, bhh, gx, nullptr, 2048, 1024, 512, 0);
  aux_kernel<<<2048, 256, 0, stream>>>(feat, auxw, auxb, outp);
  lstm_mfma<<<128, 1024, 0, stream>>>(gx, whhb, starts, h0, c0,
                                      ord_b, ord_t0, ord_len, nseg, hseq);
  heads_kernel<<<2048, 64, 0, stream>>>(hseq, actions, aw, ab, cw, cb, outp);
}

// Round 5
// 773.143 us; speedup vs baseline: 1.8123x; 1.0328x over previous
//
#include <hip/hip_runtime.h>
#include <hip/hip_bf16.h>
#include <cstddef>

typedef __attribute__((ext_vector_type(8))) short bf16x8;
typedef __attribute__((ext_vector_type(4))) float f32x4;

// ---------------------------------------------------------------------------
// Workspace byte offsets
// ---------------------------------------------------------------------------
static constexpr size_t OFF_X1B   = 0;          // bf16 x1 CL [2048][20][20][32]
static constexpr size_t OFF_X2B   = 52428800;   // bf16 x2 CL [2048][9][9][64]
static constexpr size_t OFF_X3B   = 73662464;   // bf16 x3 rows [2048][3136]
static constexpr size_t OFF_FEATB = 86507520;   // bf16 feat [2048][512]
static constexpr size_t OFF_W2B   = 88604672;   // bf16 [64][512]
static constexpr size_t OFF_W3B   = 88670208;   // bf16 [64][576]
static constexpr size_t OFF_FCWB  = 88743936;   // bf16 [512][3136]
static constexpr size_t OFF_WIHB  = 91955200;   // bf16 [1024][512]
static constexpr size_t OFF_FEAT  = 93003776;   // f32 [2048][512]
static constexpr size_t OFF_GX    = 97198080;   // f32 [2048][1024]
static constexpr size_t OFF_HSEQ  = 105586688;  // f32 [2048][256]
static constexpr size_t OFF_W1B   = 108732416;  // bf16 [32][256]
static constexpr size_t OFF_WHHB  = 108748800;  // bf16 [1024][256] straight copy
static constexpr size_t OFF_ORDB  = 109273088;  // int[2048]
static constexpr size_t OFF_ORDT0 = 109281280;  // int[2048]
static constexpr size_t OFF_ORDLEN= 109289472;  // int[2048]
static constexpr size_t OFF_NSEG  = 109297664;  // int[1]

__device__ __forceinline__ float sigmoidf_(float x) {
  return 1.0f / (1.0f + __expf(-x));
}
__device__ __forceinline__ float tanhf_(float x) {
  // tanh(x) = 1 - 2/(e^{2x}+1), fast-exp version (|err| ~1e-6 rel, fine here)
  return 1.0f - 2.0f / (__expf(2.0f * x) + 1.0f);
}

// ---------------------------------------------------------------------------
// Prep: bf16-convert + reorder weights
// ---------------------------------------------------------------------------
__global__ __launch_bounds__(256) void prep_kernel(
    const float* __restrict__ c1w, const float* __restrict__ c2w,
    const float* __restrict__ c3w, const float* __restrict__ fcw,
    const float* __restrict__ wih, const float* __restrict__ whh,
    __hip_bfloat16* __restrict__ w1b,
    __hip_bfloat16* __restrict__ w2b, __hip_bfloat16* __restrict__ w3b,
    __hip_bfloat16* __restrict__ fcwb, __hip_bfloat16* __restrict__ wihb,
    __hip_bfloat16* __restrict__ whhb) {
  int i = blockIdx.x * 256 + threadIdx.x;
  if (i < 32768) {                          // w2b: k=(ky*4+kx)*32+ci
    int o = i >> 9, k = i & 511;
    int pos = k >> 5, ci = k & 31;
    int ky = pos >> 2, kx = pos & 3;
    w2b[i] = __float2bfloat16(c2w[o * 512 + ci * 16 + ky * 4 + kx]);
  } else if (i < 69632) {                   // w3b: k=(ky*3+kx)*64+ci
    int j = i - 32768;
    int o = j / 576, k = j - o * 576;
    int pos = k >> 6, ci = k & 63;
    int ky = pos / 3, kx = pos - ky * 3;
    w3b[j] = __float2bfloat16(c3w[o * 576 + ci * 9 + ky * 3 + kx]);
  } else if (i < 1675264) {                 // fcwb: k=sp*64+ci
    int j = i - 69632;
    int o = j / 3136, k = j - o * 3136;
    int sp = k >> 6, ci = k & 63;
    fcwb[j] = __float2bfloat16(fcw[o * 3136 + ci * 49 + sp]);
  } else if (i < 2199552) {                 // wihb: native
    int j = i - 1675264;
    wihb[j] = __float2bfloat16(wih[j]);
  } else if (i < 2461696) {                 // whhb: straight bf16 copy [1024][256]
    int j = i - 2199552;
    whhb[j] = __float2bfloat16(whh[j]);
  } else if (i < 2469888) {                 // w1b: k=ky*32+ci*8+kx, *(1/255)
    int j = i - 2461696;
    int oc = j >> 8, k = j & 255;
    int ky = k >> 5, rem = k & 31;
    int ci = rem >> 3, kx = rem & 7;
    w1b[j] = __float2bfloat16(c1w[oc * 256 + ci * 64 + ky * 8 + kx] * (1.0f / 255.0f));
  }
}

// ---------------------------------------------------------------------------
// Segment planning: counting-sort segments by length desc, groups of 16.
// ---------------------------------------------------------------------------
__global__ __launch_bounds__(256) void plan_kernel(
    const float* __restrict__ starts, int* __restrict__ ord_b,
    int* __restrict__ ord_t0, int* __restrict__ ord_len,
    int* __restrict__ nseg_out) {
  __shared__ int s_t0[2048];
  __shared__ int s_len[2048];
  __shared__ int cnt[16];
  __shared__ int hist[132];
  __shared__ int off[132];
  const int tid = threadIdx.x;
  if (tid < 16) {
    int b = tid, c = 0;
    for (int t = 0; t < 128; ++t) {
      float s = starts[t * 16 + b];
      if (t == 0 || s != 0.0f) {
        if (c > 0) s_len[b * 128 + c - 1] = t - s_t0[b * 128 + c - 1];
        s_t0[b * 128 + c] = t;
        ++c;
      }
    }
    s_len[b * 128 + c - 1] = 128 - s_t0[b * 128 + c - 1];
    cnt[b] = c;
  }
  if (tid < 132) hist[tid] = 0;
  __syncthreads();
  for (int idx = tid; idx < 2048; idx += 256) {
    int b = idx >> 7, i = idx & 127;
    if (i < cnt[b]) atomicAdd(&hist[s_len[idx]], 1);
  }
  __syncthreads();
  if (tid == 0) {
    int running = 0;
    for (int L = 128; L >= 1; --L) { off[L] = running; running += hist[L]; }
    *nseg_out = running;
  }
  __syncthreads();
  for (int idx = tid; idx < 2048; idx += 256) {
    int b = idx >> 7, i = idx & 127;
    if (i < cnt[b]) {
      int len = s_len[idx];
      int pos = atomicAdd(&off[len], 1);
      ord_b[pos] = b;
      ord_t0[pos] = s_t0[idx];
      ord_len[pos] = len;
    }
  }
}

// ---------------------------------------------------------------------------
// conv1 as implicit-im2col bf16 MFMA GEMM. M=819200, N=32, K=256.
// ---------------------------------------------------------------------------
__global__ __launch_bounds__(256) void conv1_mfma(
    const float* __restrict__ obs, const __hip_bfloat16* __restrict__ w1b,
    const float* __restrict__ b1, __hip_bfloat16* __restrict__ x1b) {
  constexpr int LDK = 40;
  __shared__ __align__(16) __hip_bfloat16 As[128 * LDK];
  __shared__ __align__(16) __hip_bfloat16 Ws[32 * LDK];
  const int tid = threadIdx.x;
  const int m0 = blockIdx.x * 128;
  const int l = tid & 63;
  const int wv = tid >> 6;
  const int lane16 = l & 15;
  const int quad = l >> 4;
  const int m_base = wv * 32;

  f32x4 acc[2][2] = {};

  const float* arow[2];
  int arw[2], acp[2];
#pragma unroll
  for (int c = 0; c < 2; ++c) {
    const int id = tid + c * 256;
    const int row = id >> 2, cpos = id & 3;
    arw[c] = row; acp[c] = cpos;
    const int m = m0 + row;
    const int n = m / 400, sp = m - n * 400;
    const int oy = sp / 20, ox = sp - oy * 20;
    arow[c] = obs + (size_t)n * 28224 + cpos * 7056 + (oy * 4) * 84 + ox * 4;
  }
  const int wrow = tid >> 2, wcp = tid & 3;
  const __hip_bfloat16* wsrc = w1b + wrow * 256 + wcp * 8;

  for (int s = 0; s < 8; ++s) {
    float4 p[2], q[2];
#pragma unroll
    for (int c = 0; c < 2; ++c) {
      const float* r = arow[c] + s * 84;
      p[c] = *(const float4*)r;
      q[c] = *(const float4*)(r + 4);
    }
    uint4 wval;
    if (tid < 128) wval = *(const uint4*)(wsrc + s * 32);
    __syncthreads();
#pragma unroll
    for (int c = 0; c < 2; ++c) {
      __hip_bfloat16* d = &As[arw[c] * LDK + acp[c] * 8];
      d[0] = __float2bfloat16(p[c].x); d[1] = __float2bfloat16(p[c].y);
      d[2] = __float2bfloat16(p[c].z); d[3] = __float2bfloat16(p[c].w);
      d[4] = __float2bfloat16(q[c].x); d[5] = __float2bfloat16(q[c].y);
      d[6] = __float2bfloat16(q[c].z); d[7] = __float2bfloat16(q[c].w);
    }
    if (tid < 128) *(uint4*)&Ws[wrow * LDK + wcp * 8] = wval;
    __syncthreads();
    const bf16x8 a0 = *(const bf16x8*)&As[(m_base + lane16) * LDK + quad * 8];
    const bf16x8 a1 = *(const bf16x8*)&As[(m_base + 16 + lane16) * LDK + quad * 8];
#pragma unroll
    for (int nf = 0; nf < 2; ++nf) {
      const bf16x8 b = *(const bf16x8*)&Ws[(nf * 16 + lane16) * LDK + quad * 8];
      acc[0][nf] = __builtin_amdgcn_mfma_f32_16x16x32_bf16(a0, b, acc[0][nf], 0, 0, 0);
      acc[1][nf] = __builtin_amdgcn_mfma_f32_16x16x32_bf16(a1, b, acc[1][nf], 0, 0, 0);
    }
  }
#pragma unroll
  for (int nf = 0; nf < 2; ++nf) {
    const int col = nf * 16 + lane16;
    const float bb = b1[col];
#pragma unroll
    for (int mf = 0; mf < 2; ++mf) {
#pragma unroll
      for (int r = 0; r < 4; ++r) {
        const int row = m0 + m_base + mf * 16 + quad * 4 + r;
        const float v = fmaxf(acc[mf][nf][r] + bb, 0.f);
        x1b[(size_t)row * 32 + col] = __float2bfloat16(v);
      }
    }
  }
}

// ---------------------------------------------------------------------------
// Unified bf16 MFMA NT-GEMM (unchanged from R3)
// ---------------------------------------------------------------------------
template<int BM, int MODE>
__global__ __launch_bounds__(256) void gemm_mfma(
    const __hip_bfloat16* __restrict__ Abase,
    const __hip_bfloat16* __restrict__ Wb,
    const float* __restrict__ bias1, const float* __restrict__ bias2,
    float* __restrict__ Cf, __hip_bfloat16* __restrict__ Cb,
    const int M, const int N, const int K, const int relu) {
  constexpr int LDK = 40;
  __shared__ __align__(16) __hip_bfloat16 As[BM * LDK];
  __shared__ __align__(16) __hip_bfloat16 Ws[64 * LDK];
  const int tid = threadIdx.x;
  const int m0 = blockIdx.y * BM;
  const int n0 = blockIdx.x * 64;
  const int l = tid & 63;
  const int wv = tid >> 6;
  const int lane16 = l & 15;
  const int quad = l >> 4;
  constexpr int NF = (BM == 128) ? 4 : 2;
  const int m_base = (BM == 128) ? wv * 32 : (wv & 1) * 32;
  const int n_base = (BM == 128) ? 0 : (wv >> 1) * 32;
  constexpr int NCA = (BM == 128) ? 2 : 1;

  f32x4 acc[2][NF] = {};

  const __hip_bfloat16* arow[NCA];
  int acp[NCA];
#pragma unroll
  for (int c = 0; c < NCA; ++c) {
    const int id = tid + c * 256;
    const int row = id >> 2, cpos = id & 3;
    const int m = m0 + row;
    acp[c] = cpos;
    if (MODE == 0) {
      arow[c] = Abase + (size_t)m * K + cpos * 8;
    } else if (MODE == 1) {
      const int n = m / 81, sp = m - n * 81;
      const int oy = sp / 9, ox = sp - oy * 9;
      arow[c] = Abase + ((n * 20 + oy * 2) * 20 + ox * 2) * 32 + cpos * 8;
    } else {
      const int n = m / 49, sp = m - n * 49;
      const int oy = sp / 7, ox = sp - oy * 7;
      arow[c] = Abase + ((n * 9 + oy) * 9 + ox) * 64 + cpos * 8;
    }
  }
  const int wrow = tid >> 2, wcp = tid & 3;
  const __hip_bfloat16* wsrc = Wb + (size_t)(n0 + wrow) * K + wcp * 8;

  const int ksteps = K >> 5;
  for (int s = 0; s < ksteps; ++s) {
    uint4 av[NCA];
#pragma unroll
    for (int c = 0; c < NCA; ++c) {
      const __hip_bfloat16* p;
      if (MODE == 0) {
        p = arow[c] + s * 32;
      } else if (MODE == 1) {
        p = arow[c] + ((s >> 2) * 20 + (s & 3)) * 32;
      } else {
        const int pos = s >> 1;
        const int ky = pos / 3, kx = pos - ky * 3;
        p = arow[c] + (ky * 9 + kx) * 64 + (s & 1) * 32;
      }
      av[c] = *(const uint4*)p;
    }
    const uint4 wval = *(const uint4*)(wsrc + s * 32);
    __syncthreads();
#pragma unroll
    for (int c = 0; c < NCA; ++c) {
      const int row = (tid + c * 256) >> 2;
      *(uint4*)&As[row * LDK + acp[c] * 8] = av[c];
    }
    *(uint4*)&Ws[wrow * LDK + wcp * 8] = wval;
    __syncthreads();
    const bf16x8 a0 = *(const bf16x8*)&As[(m_base + lane16) * LDK + quad * 8];
    const bf16x8 a1 = *(const bf16x8*)&As[(m_base + 16 + lane16) * LDK + quad * 8];
#pragma unroll
    for (int nf = 0; nf < NF; ++nf) {
      const bf16x8 b = *(const bf16x8*)&Ws[(n_base + nf * 16 + lane16) * LDK + quad * 8];
      acc[0][nf] = __builtin_amdgcn_mfma_f32_16x16x32_bf16(a0, b, acc[0][nf], 0, 0, 0);
      acc[1][nf] = __builtin_amdgcn_mfma_f32_16x16x32_bf16(a1, b, acc[1][nf], 0, 0, 0);
    }
  }
#pragma unroll
  for (int nf = 0; nf < NF; ++nf) {
    const int col = n0 + n_base + nf * 16 + lane16;
    float bb = bias1[col];
    if (bias2) bb += bias2[col];
#pragma unroll
    for (int mf = 0; mf < 2; ++mf) {
#pragma unroll
      for (int r = 0; r < 4; ++r) {
        const int row = m0 + m_base + mf * 16 + quad * 4 + r;
        float v = acc[mf][nf][r] + bb;
        if (relu) v = fmaxf(v, 0.f);
        if (Cf) Cf[(size_t)row * N + col] = v;
        if (Cb) Cb[(size_t)row * N + col] = __float2bfloat16(v);
      }
    }
  }
}

// ---------------------------------------------------------------------------
// Grouped-segment MFMA LSTM v2. 16 waves/block = 4 waves/SIMD => hard cap of
// 128 VGPR/wave (512/SIMD pool). R3's bfrag[4][8]=128 VGPRs spilled to
// scratch (VGPR_Count=64, ~10us/step scratch reload). v2: HALF the B-frags
// resident (bfrag[2][8]=64 VGPRs, cols wv*64..+31), other half streamed from
// L2 each step (256 KB/block-step, line-optimal). ks-outer MFMA loop keeps
// afr transient; gx loads moved to the update phase to shrink live set.
// ---------------------------------------------------------------------------
__global__ __launch_bounds__(1024, 4) void lstm_mfma(
    const float* __restrict__ gx, const __hip_bfloat16* __restrict__ whhb,
    const float* __restrict__ starts, const float* __restrict__ h0,
    const float* __restrict__ c0, const int* __restrict__ ord_b,
    const int* __restrict__ ord_t0, const int* __restrict__ ord_len,
    const int* __restrict__ nseg_p, float* __restrict__ hseq) {
  constexpr int LDH = 264;   // bf16 row stride (256+8)
  constexpr int PS  = 1028;  // f32 row stride (1024+4)
  __shared__ __align__(16) __hip_bfloat16 h_lds[16 * LDH];
  __shared__ __align__(16) float pre[16 * PS];
  __shared__ int sg_b[16], sg_t0[16], sg_len[16];
  const int g = blockIdx.x;
  const int nseg = *nseg_p;
  if (g * 16 >= nseg) return;
  const int tid = threadIdx.x;
  const int wv = tid >> 6;      // 0..15
  const int l = tid & 63;
  const int lane16 = l & 15, quad = l >> 4;
  if (tid < 16) {
    const int s = g * 16 + tid;
    sg_b[tid] = (s < nseg) ? ord_b[s] : 0;
    sg_t0[tid] = (s < nseg) ? ord_t0[s] : 0;
    sg_len[tid] = (s < nseg) ? ord_len[s] : 0;
  }
  __syncthreads();
  // Resident B frags: cols wv*64 + nt*16 + lane16, nt in {0,1}  (64 VGPRs)
  bf16x8 bfrag[2][8];
#pragma unroll
  for (int nt = 0; nt < 2; ++nt)
#pragma unroll
    for (int ks = 0; ks < 8; ++ks)
      bfrag[nt][ks] = *(const bf16x8*)&whhb[
          (size_t)(wv * 64 + nt * 16 + lane16) * 256 + ks * 32 + quad * 8];
  // Streamed B base pointers for nt=2,3
  const __hip_bfloat16* bs2 = &whhb[(size_t)(wv * 64 + 32 + lane16) * 256 + quad * 8];
  const __hip_bfloat16* bs3 = &whhb[(size_t)(wv * 64 + 48 + lane16) * 256 + quad * 8];

  const int m_own = wv;
  const int u = l * 4;
  const int b_own = sg_b[m_own];
  const int t0_own = sg_t0[m_own];
  const int len_own = sg_len[m_own];
  float4 c_reg = make_float4(0.f, 0.f, 0.f, 0.f);
  {
    float4 hv = make_float4(0.f, 0.f, 0.f, 0.f);
    if (len_own > 0 && t0_own == 0) {
      const float keep = 1.0f - starts[b_own];
      const float4 h4 = *(const float4*)&h0[b_own * 256 + u];
      const float4 c4 = *(const float4*)&c0[b_own * 256 + u];
      hv = make_float4(h4.x * keep, h4.y * keep, h4.z * keep, h4.w * keep);
      c_reg = make_float4(c4.x * keep, c4.y * keep, c4.z * keep, c4.w * keep);
    }
    __hip_bfloat16* hd = &h_lds[m_own * LDH + u];
    hd[0] = __float2bfloat16(hv.x); hd[1] = __float2bfloat16(hv.y);
    hd[2] = __float2bfloat16(hv.z); hd[3] = __float2bfloat16(hv.w);
  }
  const int maxlen = sg_len[0];  // sorted desc within group
  for (int tt = 0; tt < maxlen; ++tt) {
    __syncthreads();  // h_lds ready
    f32x4 acc[4] = {};
#pragma unroll
    for (int ks = 0; ks < 8; ++ks) {
      const bf16x8 b2 = *(const bf16x8*)(bs2 + ks * 32);
      const bf16x8 b3 = *(const bf16x8*)(bs3 + ks * 32);
      const bf16x8 a = *(const bf16x8*)&h_lds[lane16 * LDH + ks * 32 + quad * 8];
      acc[0] = __builtin_amdgcn_mfma_f32_16x16x32_bf16(a, bfrag[0][ks], acc[0], 0, 0, 0);
      acc[1] = __builtin_amdgcn_mfma_f32_16x16x32_bf16(a, bfrag[1][ks], acc[1], 0, 0, 0);
      acc[2] = __builtin_amdgcn_mfma_f32_16x16x32_bf16(a, b2, acc[2], 0, 0, 0);
      acc[3] = __builtin_amdgcn_mfma_f32_16x16x32_bf16(a, b3, acc[3], 0, 0, 0);
    }
    // scatter pre-activations: D[m=quad*4+r][n=wv*64+nt*16+lane16]
#pragma unroll
    for (int nt = 0; nt < 4; ++nt)
#pragma unroll
      for (int r = 0; r < 4; ++r)
        pre[(quad * 4 + r) * PS + wv * 64 + nt * 16 + lane16] = acc[nt][r];
    __syncthreads();
    if (tt < len_own) {
      const int t = t0_own + tt;
      const size_t gbase = (size_t)(t * 16 + b_own) * 1024 + u;
      const float4 g0 = *(const float4*)&gx[gbase];
      const float4 g1 = *(const float4*)&gx[gbase + 256];
      const float4 g2 = *(const float4*)&gx[gbase + 512];
      const float4 g3 = *(const float4*)&gx[gbase + 768];
      const float4 p0 = *(const float4*)&pre[m_own * PS + u];
      const float4 p1 = *(const float4*)&pre[m_own * PS + u + 256];
      const float4 p2 = *(const float4*)&pre[m_own * PS + u + 512];
      const float4 p3 = *(const float4*)&pre[m_own * PS + u + 768];
      const float i0 = sigmoidf_(p0.x + g0.x), i1 = sigmoidf_(p0.y + g0.y),
                  i2 = sigmoidf_(p0.z + g0.z), i3 = sigmoidf_(p0.w + g0.w);
      const float f0 = sigmoidf_(p1.x + g1.x), f1 = sigmoidf_(p1.y + g1.y),
                  f2 = sigmoidf_(p1.z + g1.z), f3 = sigmoidf_(p1.w + g1.w);
      const float q0 = tanhf_(p2.x + g2.x), q1 = tanhf_(p2.y + g2.y),
                  q2 = tanhf_(p2.z + g2.z), q3 = tanhf_(p2.w + g2.w);
      const float o0 = sigmoidf_(p3.x + g3.x), o1 = sigmoidf_(p3.y + g3.y),
                  o2 = sigmoidf_(p3.z + g3.z), o3 = sigmoidf_(p3.w + g3.w);
      c_reg.x = fmaf(f0, c_reg.x, i0 * q0);
      c_reg.y = fmaf(f1, c_reg.y, i1 * q1);
      c_reg.z = fmaf(f2, c_reg.z, i2 * q2);
      c_reg.w = fmaf(f3, c_reg.w, i3 * q3);
      const float4 h4 = make_float4(o0 * tanhf_(c_reg.x), o1 * tanhf_(c_reg.y),
                                    o2 * tanhf_(c_reg.z), o3 * tanhf_(c_reg.w));
      __hip_bfloat16* hd = &h_lds[m_own * LDH + u];
      hd[0] = __float2bfloat16(h4.x); hd[1] = __float2bfloat16(h4.y);
      hd[2] = __float2bfloat16(h4.z); hd[3] = __float2bfloat16(h4.w);
      *(float4*)&hseq[(size_t)(t * 16 + b_own) * 256 + u] = h4;
    }
  }
}

// ---------------------------------------------------------------------------
// aux head
// ---------------------------------------------------------------------------
__global__ __launch_bounds__(256) void aux_kernel(
    const float* __restrict__ feat, const float* __restrict__ aux_w,
    const float* __restrict__ aux_b, float* __restrict__ outp) {
  const int tb = blockIdx.x;
  const int tid = threadIdx.x;
  __shared__ float red[256];
  const float* f = feat + (size_t)tb * 512;
  red[tid] = f[tid] * aux_w[tid] + f[tid + 256] * aux_w[tid + 256];
  __syncthreads();
  for (int s = 128; s > 0; s >>= 1) {
    if (tid < s) red[tid] += red[tid + s];
    __syncthreads();
  }
  if (tid == 0) outp[6144 + tb] = red[0] + aux_b[0];
}

// ---------------------------------------------------------------------------
// heads v2: wave-per-row. Lane l owns k=4l..4l+3; 19 float4-dot partials then
// 64-lane butterfly reduce; softmax/entropy computed redundantly on all lanes.
// ---------------------------------------------------------------------------
__global__ __launch_bounds__(256) void heads_kernel(
    const float* __restrict__ hseq, const int* __restrict__ actions,
    const float* __restrict__ actor_w, const float* __restrict__ actor_b,
    const float* __restrict__ critic_w, const float* __restrict__ critic_b,
    float* __restrict__ outp) {
  const int tid = threadIdx.x;
  const int wv = tid >> 6, l = tid & 63;
  const int tb = blockIdx.x * 4 + wv;
  const float4 h4 = *(const float4*)&hseq[(size_t)tb * 256 + l * 4];
  float part[19];
#pragma unroll
  for (int o = 0; o < 18; ++o) {
    const float4 w = *(const float4*)&actor_w[o * 256 + l * 4];
    part[o] = h4.x * w.x + h4.y * w.y + h4.z * w.z + h4.w * w.w;
  }
  {
    const float4 w = *(const float4*)&critic_w[l * 4];
    part[18] = h4.x * w.x + h4.y * w.y + h4.z * w.z + h4.w * w.w;
  }
#pragma unroll
  for (int off = 32; off > 0; off >>= 1) {
#pragma unroll
    for (int o = 0; o < 19; ++o) part[o] += __shfl_xor(part[o], off);
  }
  float lg[18];
  float m = -1e30f;
#pragma unroll
  for (int o = 0; o < 18; ++o) {
    lg[o] = part[o] + actor_b[o];
    m = fmaxf(m, lg[o]);
  }
  float se = 0.f;
#pragma unroll
  for (int o = 0; o < 18; ++o) se += __expf(lg[o] - m);
  const float lse = __logf(se);
  float ent = 0.f;
#pragma unroll
  for (int o = 0; o < 18; ++o) {
    const float lp = lg[o] - m - lse;
    ent -= __expf(lp) * lp;
  }
  if (l == 0) {
    const int a = actions[tb];
    outp[tb] = lg[a] - m - lse;
    outp[2048 + tb] = ent;
    outp[4096 + tb] = part[18] + critic_b[0];
  }
}

// ---------------------------------------------------------------------------
// launch
// ---------------------------------------------------------------------------
extern "C" void kernel_launch(void* const* d_in, const int* in_sizes, int n_in,
                              void* d_out, int out_size, void* d_ws, size_t ws_size,
                              hipStream_t stream) {
  const float* obs     = (const float*)d_in[0];
  const int*   actions = (const int*)d_in[1];
  const float* starts  = (const float*)d_in[2];
  const float* h0      = (const float*)d_in[3];
  const float* c0      = (const float*)d_in[4];
  const float* c1w     = (const float*)d_in[5];
  const float* c1b     = (const float*)d_in[6];
  const float* c2w     = (const float*)d_in[7];
  const float* c2b     = (const float*)d_in[8];
  const float* c3w     = (const float*)d_in[9];
  const float* c3b     = (const float*)d_in[10];
  const float* fcw     = (const float*)d_in[11];
  const float* fcb     = (const float*)d_in[12];
  const float* wih     = (const float*)d_in[13];
  const float* whh     = (const float*)d_in[14];
  const float* bih     = (const float*)d_in[15];
  const float* bhh     = (const float*)d_in[16];
  const float* aw      = (const float*)d_in[17];
  const float* ab      = (const float*)d_in[18];
  const float* cw      = (const float*)d_in[19];
  const float* cb      = (const float*)d_in[20];
  const float* auxw    = (const float*)d_in[21];
  const float* auxb    = (const float*)d_in[22];

  char* ws = (char*)d_ws;
  __hip_bfloat16* x1b   = (__hip_bfloat16*)(ws + OFF_X1B);
  __hip_bfloat16* x2b   = (__hip_bfloat16*)(ws + OFF_X2B);
  __hip_bfloat16* x3b   = (__hip_bfloat16*)(ws + OFF_X3B);
  __hip_bfloat16* featb = (__hip_bfloat16*)(ws + OFF_FEATB);
  __hip_bfloat16* w2b   = (__hip_bfloat16*)(ws + OFF_W2B);
  __hip_bfloat16* w3b   = (__hip_bfloat16*)(ws + OFF_W3B);
  __hip_bfloat16* fcwb  = (__hip_bfloat16*)(ws + OFF_FCWB);
  __hip_bfloat16* wihb  = (__hip_bfloat16*)(ws + OFF_WIHB);
  __hip_bfloat16* w1b   = (__hip_bfloat16*)(ws + OFF_W1B);
  __hip_bfloat16* whhb  = (__hip_bfloat16*)(ws + OFF_WHHB);
  float* feat = (float*)(ws + OFF_FEAT);
  float* gx   = (float*)(ws + OFF_GX);
  float* hseq = (float*)(ws + OFF_HSEQ);
  int* ord_b   = (int*)(ws + OFF_ORDB);
  int* ord_t0  = (int*)(ws + OFF_ORDT0);
  int* ord_len = (int*)(ws + OFF_ORDLEN);
  int* nseg    = (int*)(ws + OFF_NSEG);
  float* outp = (float*)d_out;

  prep_kernel<<<9648, 256, 0, stream>>>(c1w, c2w, c3w, fcw, wih, whh,
                                        w1b, w2b, w3b, fcwb, wihb, whhb);
  plan_kernel<<<1, 256, 0, stream>>>(starts, ord_b, ord_t0, ord_len, nseg);
  conv1_mfma<<<6400, 256, 0, stream>>>(obs, w1b, c1b, x1b);
  gemm_mfma<128, 1><<<dim3(1, 1296), 256, 0, stream>>>(
      x1b, w2b, c2b, nullptr, nullptr, x2b, 165888, 64, 512, 1);
  gemm_mfma<128, 2><<<dim3(1, 784), 256, 0, stream>>>(
      x2b, w3b, c3b, nullptr, nullptr, x3b, 100352, 64, 576, 1);
  gemm_mfma<64, 0><<<dim3(8, 32), 256, 0, stream>>>(
      x3b, fcwb, fcb, nullptr, feat, featb, 2048, 512, 3136, 1);
  gemm_mfma<64, 0><<<dim3(16, 32), 256, 0, stream>>>(
      featb, wihb, bih, bhh, gx, nullptr, 2048, 1024, 512, 0);
  aux_kernel<<<2048, 256, 0, stream>>>(feat, auxw, auxb, outp);
  lstm_mfma<<<128, 1024, 0, stream>>>(gx, whhb, starts, h0, c0,
                                      ord_b, ord_t0, ord_len, nseg, hseq);
  heads_kernel<<<512, 256, 0, stream>>>(hseq, actions, aw, ab, cw, cb, outp);
}